// Round 6
// baseline (1211.005 us; speedup 1.0000x reference)
//
#include <hip/hip_runtime.h>
#include <math.h>

constexpr int FDIM = 128;   // IN == HID
constexpr int ODIM = 64;    // NC
constexpr int NB   = 256;   // scan blocks per graph

// ---------------- column stats (deterministic two-stage) ----------------
template<int C>
__global__ void k_colstats(const float* __restrict__ X, int N, float* __restrict__ partial) {
    const int c = threadIdx.x;          // blockDim.x == C
    const int nb = gridDim.x;
    const int rows_per = (N + nb - 1) / nb;
    const int r0 = blockIdx.x * rows_per;
    const int r1 = min(N, r0 + rows_per);
    float s = 0.f, ss = 0.f;
    for (int r = r0; r < r1; ++r) {
        float v = X[(size_t)r * C + c];
        s += v;
        ss += v * v;
    }
    partial[(size_t)blockIdx.x * (2 * C) + c]     = s;
    partial[(size_t)blockIdx.x * (2 * C) + C + c] = ss;
}

template<int C>
__global__ void k_colstats_fin(const float* __restrict__ partial, int nb, int N,
                               const float* __restrict__ gamma, const float* __restrict__ beta,
                               float* __restrict__ scale, float* __restrict__ shift) {
    const int c = threadIdx.x;          // blockDim.x == C
    float s = 0.f, ss = 0.f;
    for (int b = 0; b < nb; ++b) {
        s  += partial[(size_t)b * (2 * C) + c];
        ss += partial[(size_t)b * (2 * C) + C + c];
    }
    const float mu  = s / (float)N;
    const float var = ss / (float)N - mu * mu;
    const float sc  = gamma[c] * rsqrtf(var + 1e-5f);
    scale[c] = sc;
    shift[c] = beta[c] - mu * sc;
}

// ---------------- degree (3 graphs, blockIdx.y) ----------------
__global__ void k_deg3(const int* __restrict__ d0, const int* __restrict__ d1,
                       const int* __restrict__ d2, int e0, int e1, int e2,
                       unsigned* __restrict__ deg, int N) {
    const int g = blockIdx.y;
    const int* dst = (g == 0) ? d0 : (g == 1) ? d1 : d2;
    const int E = (g == 0) ? e0 : (g == 1) ? e1 : e2;
    unsigned* dg = deg + (size_t)g * N;
    int i = blockIdx.x * blockDim.x + threadIdx.x;
    const int stride = gridDim.x * blockDim.x;
    for (; i < E; i += stride) atomicAdd(&dg[dst[i]], 1u);
}

// ---------------- parallel deterministic exclusive scan (3 kernels) ----------------
__global__ __launch_bounds__(256) void k_bsum(const unsigned* __restrict__ deg,
                                              unsigned* __restrict__ bsum, int N) {
    const int g = blockIdx.y, b = blockIdx.x, t = threadIdx.x;
    const unsigned* d = deg + (size_t)g * N;
    const int chunk = (N + gridDim.x - 1) / gridDim.x;
    const int i0 = b * chunk, i1 = min(N, i0 + chunk);
    unsigned s = 0;
    for (int i = i0 + t; i < i1; i += 256) s += d[i];
    __shared__ unsigned red[256];
    red[t] = s;
    __syncthreads();
    for (int ofs = 128; ofs; ofs >>= 1) {
        if (t < ofs) red[t] += red[t + ofs];
        __syncthreads();
    }
    if (t == 0) bsum[g * gridDim.x + b] = red[0];
}

__global__ void k_bscan(unsigned* __restrict__ bsum, int n) {
    const int t = threadIdx.x;
    __shared__ unsigned ps[3 * NB];
    unsigned v = (t < n) ? bsum[t] : 0u;
    ps[t] = v;
    __syncthreads();
    for (int ofs = 1; ofs < NB; ofs <<= 1) {
        const unsigned add = ((t & (NB - 1)) >= ofs) ? ps[t - ofs] : 0u;
        __syncthreads();
        ps[t] += add;
        __syncthreads();
    }
    if (t < n) bsum[t] = ps[t] - v;   // exclusive within each graph segment
}

__global__ __launch_bounds__(256) void k_scan2(const unsigned* __restrict__ deg,
                                               const unsigned* __restrict__ bofs,
                                               int* __restrict__ off, int* __restrict__ cur,
                                               float* __restrict__ rinv, int N) {
    const int g = blockIdx.y, b = blockIdx.x, t = threadIdx.x;
    const unsigned* d = deg + (size_t)g * N;
    int* o = off + (size_t)g * N;
    int* c = cur + (size_t)g * N;
    float* rv = rinv + (size_t)g * N;
    const int chunk = (N + gridDim.x - 1) / gridDim.x;
    const int i0 = b * chunk, i1 = min(N, i0 + chunk);
    unsigned run = bofs[g * gridDim.x + b];
    __shared__ unsigned ps[256];
    for (int base = i0; base < i1; base += 256) {
        const int i = base + t;
        const unsigned v = (i < i1) ? d[i] : 0u;
        ps[t] = v;
        __syncthreads();
        for (int ofs = 1; ofs < 256; ofs <<= 1) {
            const unsigned add = (t >= ofs) ? ps[t - ofs] : 0u;
            __syncthreads();
            ps[t] += add;
            __syncthreads();
        }
        if (i < i1) {
            const unsigned ex = run + ps[t] - v;
            o[i] = (int)ex;
            c[i] = (int)ex;
            rv[i] = 1.0f / ((float)v + 1.0f);
        }
        run += ps[255];
        __syncthreads();
    }
}

// ---------------- fill CSR neighbor lists (3 graphs, blockIdx.y) ----------------
__global__ void k_fill3(const int* __restrict__ s0, const int* __restrict__ d0,
                        const int* __restrict__ s1, const int* __restrict__ d1,
                        const int* __restrict__ s2, const int* __restrict__ d2,
                        int e0, int e1, int e2, int* __restrict__ cur,
                        int* __restrict__ n0, int* __restrict__ n1, int* __restrict__ n2,
                        int N) {
    const int g = blockIdx.y;
    const int* src = (g == 0) ? s0 : (g == 1) ? s1 : s2;
    const int* dst = (g == 0) ? d0 : (g == 1) ? d1 : d2;
    const int E = (g == 0) ? e0 : (g == 1) ? e1 : e2;
    int* nbr = (g == 0) ? n0 : (g == 1) ? n1 : n2;
    int* cu = cur + (size_t)g * N;
    int i = blockIdx.x * blockDim.x + threadIdx.x;
    const int stride = gridDim.x * blockDim.x;
    for (; i < E; i += stride) {
        const int v = dst[i];
        const int p = atomicAdd(&cu[v], 1);
        nbr[p] = src[i];
    }
}

// ---------------- fused layer-1: gather(BN1-fused) into LDS + GEMM over 3 graphs ----------------
// H[64 rows] = relu( sum_g (rinv_g*(x_v + sum_u x_u)*s1 + sh1) @ W_g1 + sum_g b_g )
__global__ __launch_bounds__(256) void k_gg1(
    const float* __restrict__ X,
    const int* __restrict__ nbr0, const int* __restrict__ nbr1, const int* __restrict__ nbr2,
    const int* __restrict__ off, const int* __restrict__ cend, const float* __restrict__ rinv,
    const float* __restrict__ s1, const float* __restrict__ sh1,
    const float* __restrict__ W1, const float* __restrict__ W2, const float* __restrict__ W3,
    const float* __restrict__ b1, const float* __restrict__ b2, const float* __restrict__ b3,
    float* __restrict__ H, int N) {
    __shared__ float As[64 * FDIM];     // 32 KB gathered A-tile (row-major)
    __shared__ float Bt[16][FDIM];      // 8 KB weight tile
    const int t = threadIdx.x;
    const int wave = t >> 6, lane = t & 63;
    const int l2 = lane * 2;
    const int row0 = blockIdx.x * 64;
    const int c0 = (t & 31) * 4;        // output col base 0..124
    const int r0 = (t >> 5) * 8;        // output row base 0..56
    const float2 sc = *(const float2*)&s1[l2];
    const float2 sh = *(const float2*)&sh1[l2];
    float acc[8][4];
    #pragma unroll
    for (int r = 0; r < 8; ++r)
        #pragma unroll
        for (int c = 0; c < 4; ++c) acc[r][c] = 0.f;

    for (int g = 0; g < 3; ++g) {
        const int* nb = (g == 0) ? nbr0 : (g == 1) ? nbr1 : nbr2;
        const float* W = (g == 0) ? W1 : (g == 1) ? W2 : W3;
        const int gb = g * N;
        // ---- gather 64 rows into As (wave w handles rows w*16..w*16+15) ----
        for (int q = 0; q < 16; ++q) {
            const int r = wave * 16 + q;
            const int node = row0 + r;
            float2 a = {0.f, 0.f};
            if (node < N) {
                const int i0 = off[gb + node], i1 = cend[gb + node];
                a = *(const float2*)&X[(size_t)node * FDIM + l2];
                int i = i0;
                for (; i + 8 <= i1; i += 8) {
                    const int u0 = nb[i],     u1 = nb[i + 1], u2 = nb[i + 2], u3 = nb[i + 3];
                    const int u4 = nb[i + 4], u5 = nb[i + 5], u6 = nb[i + 6], u7 = nb[i + 7];
                    const float2 a0 = *(const float2*)&X[(size_t)u0 * FDIM + l2];
                    const float2 a1 = *(const float2*)&X[(size_t)u1 * FDIM + l2];
                    const float2 a2 = *(const float2*)&X[(size_t)u2 * FDIM + l2];
                    const float2 a3 = *(const float2*)&X[(size_t)u3 * FDIM + l2];
                    const float2 a4 = *(const float2*)&X[(size_t)u4 * FDIM + l2];
                    const float2 a5 = *(const float2*)&X[(size_t)u5 * FDIM + l2];
                    const float2 a6 = *(const float2*)&X[(size_t)u6 * FDIM + l2];
                    const float2 a7 = *(const float2*)&X[(size_t)u7 * FDIM + l2];
                    a.x += ((a0.x + a1.x) + (a2.x + a3.x)) + ((a4.x + a5.x) + (a6.x + a7.x));
                    a.y += ((a0.y + a1.y) + (a2.y + a3.y)) + ((a4.y + a5.y) + (a6.y + a7.y));
                }
                for (; i < i1; ++i) {
                    const int u = nb[i];
                    const float2 av = *(const float2*)&X[(size_t)u * FDIM + l2];
                    a.x += av.x;
                    a.y += av.y;
                }
                const float rv = rinv[gb + node];
                a.x = fmaf(a.x * rv, sc.x, sh.x);
                a.y = fmaf(a.y * rv, sc.y, sh.y);
            }
            *(float2*)&As[r * FDIM + l2] = a;
        }
        __syncthreads();
        // ---- GEMM: acc += As @ W_g ----
        for (int kb = 0; kb < 8; ++kb) {
            const int k0 = kb * 16;
            {
                const int n = t & 127;
                const int kkb = t >> 7;     // 0..1
                #pragma unroll
                for (int it = 0; it < 8; ++it) {
                    const int kk = kkb + it * 2;
                    Bt[kk][n] = W[(size_t)(k0 + kk) * FDIM + n];
                }
            }
            __syncthreads();
            #pragma unroll
            for (int kk = 0; kk < 16; ++kk) {
                const float4 b = *(const float4*)&Bt[kk][c0];
                #pragma unroll
                for (int r = 0; r < 8; ++r) {
                    const float a = As[(r0 + r) * FDIM + k0 + kk];
                    acc[r][0] = fmaf(a, b.x, acc[r][0]);
                    acc[r][1] = fmaf(a, b.y, acc[r][1]);
                    acc[r][2] = fmaf(a, b.z, acc[r][2]);
                    acc[r][3] = fmaf(a, b.w, acc[r][3]);
                }
            }
            __syncthreads();
        }
    }
    // ---- epilogue: Σbias + ReLU ----
    float4 base;
    base.x = b1[c0 + 0] + b2[c0 + 0] + b3[c0 + 0];
    base.y = b1[c0 + 1] + b2[c0 + 1] + b3[c0 + 1];
    base.z = b1[c0 + 2] + b2[c0 + 2] + b3[c0 + 2];
    base.w = b1[c0 + 3] + b2[c0 + 3] + b3[c0 + 3];
    #pragma unroll
    for (int r = 0; r < 8; ++r) {
        const int row = row0 + r0 + r;
        if (row < N) {
            float4 o;
            o.x = fmaxf(acc[r][0] + base.x, 0.f);
            o.y = fmaxf(acc[r][1] + base.y, 0.f);
            o.z = fmaxf(acc[r][2] + base.z, 0.f);
            o.w = fmaxf(acc[r][3] + base.w, 0.f);
            *(float4*)&H[(size_t)row * FDIM + c0] = o;
        }
    }
}

// ---------------- c2[g][n] = sum_k sh2[k] * Wg[k][n] (BN2 shift folded through GEMM2) ----------------
__global__ void k_c2(const float* __restrict__ sh2,
                     const float* __restrict__ W1, const float* __restrict__ W2,
                     const float* __restrict__ W3, float* __restrict__ c2) {
    const int t = threadIdx.x;   // 192
    const int g = t >> 6, n = t & 63;
    const float* W = (g == 0) ? W1 : (g == 1) ? W2 : W3;
    float s = 0.f;
    for (int k = 0; k < 128; ++k) s = fmaf(sh2[k], W[(size_t)k * ODIM + n], s);
    c2[g * ODIM + n] = s;
}

// ---------------- GEMM2 (BN2 scale fused into A-load): U_g = (H*s2) @ W_g2 + c2_g ----------------
__global__ __launch_bounds__(256) void k_gemm2(
    const float* __restrict__ H, const float* __restrict__ s2,
    const float* __restrict__ W1, const float* __restrict__ W2, const float* __restrict__ W3,
    const float* __restrict__ c2, float* __restrict__ U, int N) {
    __shared__ float At[16][64];
    __shared__ float Bt[16][64];
    const int t = threadIdx.x;
    const int g = blockIdx.y;
    const int row0 = blockIdx.x * 64;
    const int c0 = (t & 15) * 4;     // 0..60
    const int r0 = (t >> 4) * 4;     // 0..60
    const float* Wg = (g == 0) ? W1 : (g == 1) ? W2 : W3;
    float acc[4][4];
    #pragma unroll
    for (int r = 0; r < 4; ++r)
        #pragma unroll
        for (int c = 0; c < 4; ++c) acc[r][c] = 0.f;

    for (int kb = 0; kb < 8; ++kb) {       // K = 128
        const int k0 = kb * 16;
        {
            const int kk = t & 15;
            const int rb = t >> 4;          // 0..15
            const float sv = s2[k0 + kk];
            #pragma unroll
            for (int it = 0; it < 4; ++it) {
                const int r = rb + it * 16;
                const int row = row0 + r;
                At[kk][r] = (row < N) ? H[(size_t)row * FDIM + k0 + kk] * sv : 0.f;
            }
        }
        {
            const int n = t & 63;
            const int kkb = t >> 6;         // 0..3
            #pragma unroll
            for (int it = 0; it < 4; ++it) {
                const int kk = kkb + it * 4;
                Bt[kk][n] = Wg[(size_t)(k0 + kk) * ODIM + n];
            }
        }
        __syncthreads();
        #pragma unroll
        for (int kk = 0; kk < 16; ++kk) {
            const float4 b = *(const float4*)&Bt[kk][c0];
            const float4 a = *(const float4*)&At[kk][r0];
            const float av[4] = {a.x, a.y, a.z, a.w};
            #pragma unroll
            for (int r = 0; r < 4; ++r) {
                acc[r][0] = fmaf(av[r], b.x, acc[r][0]);
                acc[r][1] = fmaf(av[r], b.y, acc[r][1]);
                acc[r][2] = fmaf(av[r], b.z, acc[r][2]);
                acc[r][3] = fmaf(av[r], b.w, acc[r][3]);
            }
        }
        __syncthreads();
    }
    const float* cg = c2 + (size_t)g * ODIM;
    float* Ug = U + (size_t)g * N * ODIM;
    #pragma unroll
    for (int r = 0; r < 4; ++r) {
        const int row = row0 + r0 + r;
        if (row < N) {
            float4 o;
            o.x = acc[r][0] + cg[c0 + 0];
            o.y = acc[r][1] + cg[c0 + 1];
            o.z = acc[r][2] + cg[c0 + 2];
            o.w = acc[r][3] + cg[c0 + 3];
            *(float4*)&Ug[(size_t)row * ODIM + c0] = o;
        }
    }
}

// ---------------- layer-2 gather + combine ----------------
__global__ __launch_bounds__(256) void k_gc64(
    const float* __restrict__ U,
    const int* __restrict__ nbr0, const int* __restrict__ nbr1, const int* __restrict__ nbr2,
    const int* __restrict__ off, const int* __restrict__ cend,
    const float* __restrict__ rinv,
    const float* __restrict__ b1, const float* __restrict__ b2, const float* __restrict__ b3,
    float* __restrict__ Z, int N) {
    const int wave = threadIdx.x >> 6;
    const int lane = threadIdx.x & 63;
    const int v = blockIdx.x * 4 + wave;
    if (v >= N) return;
    const size_t gs = (size_t)N * ODIM;
    float z = b1[lane] + b2[lane] + b3[lane];
    #pragma unroll
    for (int g = 0; g < 3; ++g) {
        const float* Ug = U + (size_t)g * gs;
        const int* nb = (g == 0) ? nbr0 : (g == 1) ? nbr1 : nbr2;
        const int i0 = off[g * N + v], i1 = cend[g * N + v];
        float s = Ug[(size_t)v * ODIM + lane];
        int i = i0;
        for (; i + 8 <= i1; i += 8) {
            const int u0 = nb[i],     u1 = nb[i + 1], u2 = nb[i + 2], u3 = nb[i + 3];
            const int u4 = nb[i + 4], u5 = nb[i + 5], u6 = nb[i + 6], u7 = nb[i + 7];
            const float a0 = Ug[(size_t)u0 * ODIM + lane];
            const float a1 = Ug[(size_t)u1 * ODIM + lane];
            const float a2 = Ug[(size_t)u2 * ODIM + lane];
            const float a3 = Ug[(size_t)u3 * ODIM + lane];
            const float a4 = Ug[(size_t)u4 * ODIM + lane];
            const float a5 = Ug[(size_t)u5 * ODIM + lane];
            const float a6 = Ug[(size_t)u6 * ODIM + lane];
            const float a7 = Ug[(size_t)u7 * ODIM + lane];
            s += ((a0 + a1) + (a2 + a3)) + ((a4 + a5) + (a6 + a7));
        }
        for (; i < i1; ++i) s += Ug[(size_t)nb[i] * ODIM + lane];
        z += s * rinv[g * N + v];
    }
    Z[(size_t)v * ODIM + lane] = z;
}

// ---------------- final: BN3 + sigmoid + row min-max + row L2, in place ----------------
__global__ __launch_bounds__(256) void k_final(float* __restrict__ Z,
                                               const float* __restrict__ scale,
                                               const float* __restrict__ shift, int N) {
    const int wave = threadIdx.x >> 6;
    const int lane = threadIdx.x & 63;
    const int row = blockIdx.x * 4 + wave;
    if (row >= N) return;
    float v = fmaf(Z[(size_t)row * ODIM + lane], scale[lane], shift[lane]);
    float s = 1.0f / (1.0f + expf(-v));
    float mn = s, mx = s;
    #pragma unroll
    for (int off = 32; off; off >>= 1) {
        mn = fminf(mn, __shfl_xor(mn, off, 64));
        mx = fmaxf(mx, __shfl_xor(mx, off, 64));
    }
    const float sc = (s - mn) / (mx - mn);
    float sq = sc * sc;
    #pragma unroll
    for (int off = 32; off; off >>= 1) sq += __shfl_xor(sq, off, 64);
    const float norm = fmaxf(sqrtf(sq), 1e-12f);
    Z[(size_t)row * ODIM + lane] = sc / norm;
}

extern "C" void kernel_launch(void* const* d_in, const int* in_sizes, int n_in,
                              void* d_out, int out_size, void* d_ws, size_t ws_size,
                              hipStream_t stream) {
    const float* x = (const float*)d_in[0];
    const int* src[3] = {(const int*)d_in[1], (const int*)d_in[3], (const int*)d_in[5]};
    const int* dst[3] = {(const int*)d_in[2], (const int*)d_in[4], (const int*)d_in[6]};
    const int E[3] = {in_sizes[1], in_sizes[3], in_sizes[5]};
    const float* W11 = (const float*)d_in[7];  const float* b11 = (const float*)d_in[8];
    const float* W21 = (const float*)d_in[9];  const float* b21 = (const float*)d_in[10];
    const float* W31 = (const float*)d_in[11]; const float* b31 = (const float*)d_in[12];
    const float* W12 = (const float*)d_in[13]; const float* b12 = (const float*)d_in[14];
    const float* W22 = (const float*)d_in[15]; const float* b22 = (const float*)d_in[16];
    const float* W32 = (const float*)d_in[17]; const float* b32 = (const float*)d_in[18];
    const float* g1  = (const float*)d_in[19]; const float* be1 = (const float*)d_in[20];
    const float* g2  = (const float*)d_in[21]; const float* be2 = (const float*)d_in[22];
    const float* g3  = (const float*)d_in[23]; const float* be3 = (const float*)d_in[24];
    const int N = in_sizes[0] / FDIM;
    float* Z = (float*)d_out;

    // ---- workspace layout (floats) ----
    float* ws   = (float*)d_ws;
    float* H    = ws;                          // N*128 (25.6 MB)
    float* U    = H + (size_t)N * FDIM;        // 3*N*64 (38.4 MB)
    float* rinv = U + (size_t)3 * N * ODIM;    // 3N
    float* partial = rinv + (size_t)3 * N;     // 65536
    float* s1  = partial + 65536;  float* sh1 = s1 + 128;
    float* s2  = sh1 + 128;        float* sh2 = s2 + 128;
    float* s3  = sh2 + 128;        float* sh3 = s3 + 64;
    float* c2  = sh3 + 64;                     // 3*64
    // int region
    unsigned* degi  = (unsigned*)(c2 + 3 * ODIM);         // 3N
    unsigned* bsum  = degi + (size_t)3 * N;               // 3*NB
    int* off  = (int*)(bsum + (size_t)3 * NB);            // 3N
    int* cur  = off + (size_t)3 * N;                      // 3N
    int* nbr  = cur + (size_t)3 * N;                      // E0+E1+E2
    int* nbrg[3];
    nbrg[0] = nbr;
    nbrg[1] = nbrg[0] + E[0];
    nbrg[2] = nbrg[1] + E[1];

    // ---- degrees + CSR build (deterministic parallel scan for offsets) ----
    hipMemsetAsync(degi, 0, (size_t)3 * N * sizeof(unsigned), stream);
    k_deg3<<<dim3(1024, 3), 256, 0, stream>>>(dst[0], dst[1], dst[2], E[0], E[1], E[2], degi, N);
    k_bsum<<<dim3(NB, 3), 256, 0, stream>>>(degi, bsum, N);
    k_bscan<<<1, 3 * NB, 0, stream>>>(bsum, 3 * NB);
    k_scan2<<<dim3(NB, 3), 256, 0, stream>>>(degi, bsum, off, cur, rinv, N);
    k_fill3<<<dim3(2048, 3), 256, 0, stream>>>(src[0], dst[0], src[1], dst[1], src[2], dst[2],
                                               E[0], E[1], E[2], cur,
                                               nbrg[0], nbrg[1], nbrg[2], N);

    // ---- BN1 stats (applied inside fused gather) ----
    k_colstats<128><<<256, 128, 0, stream>>>(x, N, partial);
    k_colstats_fin<128><<<1, 128, 0, stream>>>(partial, 256, N, g1, be1, s1, sh1);

    // ---- layer 1: fused gather + GEMM over 3 graphs, one dispatch ----
    k_gg1<<<(N + 63) / 64, 256, 0, stream>>>(x, nbrg[0], nbrg[1], nbrg[2], off, cur, rinv,
                                             s1, sh1, W11, W21, W31, b11, b21, b31, H, N);

    // ---- BN2 stats (scale fused into GEMM2 A-load, shift folded via c2) ----
    k_colstats<128><<<256, 128, 0, stream>>>(H, N, partial);
    k_colstats_fin<128><<<1, 128, 0, stream>>>(partial, 256, N, g2, be2, s2, sh2);
    k_c2<<<1, 192, 0, stream>>>(sh2, W12, W22, W32, c2);

    // ---- layer 2: GEMM first (linearity), then fused gather+combine ----
    dim3 grid2((N + 63) / 64, 3);
    k_gemm2<<<grid2, 256, 0, stream>>>(H, s2, W12, W22, W32, c2, U, N);
    const int gblocks = (N + 3) / 4;
    k_gc64<<<gblocks, 256, 0, stream>>>(U, nbrg[0], nbrg[1], nbrg[2], off, cur, rinv,
                                        b12, b22, b32, Z, N);

    // ---- BN3 + epilogue ----
    k_colstats<64><<<256, 64, 0, stream>>>(Z, N, partial);
    k_colstats_fin<64><<<1, 64, 0, stream>>>(partial, 256, N, g3, be3, s3, sh3);
    k_final<<<(N + 3) / 4, 256, 0, stream>>>(Z, s3, sh3, N);
}

// Round 7
// 1067.023 us; speedup vs baseline: 1.1349x; 1.1349x over previous
//
#include <hip/hip_runtime.h>
#include <math.h>

constexpr int FDIM = 128;   // IN == HID
constexpr int ODIM = 64;    // NC
constexpr int NB   = 256;   // scan blocks per graph

// ---------------- column stats (deterministic two-stage) ----------------
template<int C>
__global__ void k_colstats(const float* __restrict__ X, int N, float* __restrict__ partial) {
    const int c = threadIdx.x;          // blockDim.x == C
    const int nb = gridDim.x;
    const int rows_per = (N + nb - 1) / nb;
    const int r0 = blockIdx.x * rows_per;
    const int r1 = min(N, r0 + rows_per);
    float s = 0.f, ss = 0.f;
    for (int r = r0; r < r1; ++r) {
        float v = X[(size_t)r * C + c];
        s += v;
        ss += v * v;
    }
    partial[(size_t)blockIdx.x * (2 * C) + c]     = s;
    partial[(size_t)blockIdx.x * (2 * C) + C + c] = ss;
}

template<int C>
__global__ void k_colstats_fin(const float* __restrict__ partial, int nb, int N,
                               const float* __restrict__ gamma, const float* __restrict__ beta,
                               float* __restrict__ scale, float* __restrict__ shift) {
    const int c = threadIdx.x;          // blockDim.x == C
    float s = 0.f, ss = 0.f;
    for (int b = 0; b < nb; ++b) {
        s  += partial[(size_t)b * (2 * C) + c];
        ss += partial[(size_t)b * (2 * C) + C + c];
    }
    const float mu  = s / (float)N;
    const float var = ss / (float)N - mu * mu;
    const float sc  = gamma[c] * rsqrtf(var + 1e-5f);
    scale[c] = sc;
    shift[c] = beta[c] - mu * sc;
}

// ---------------- degree (3 graphs, blockIdx.y) ----------------
__global__ void k_deg3(const int* __restrict__ d0, const int* __restrict__ d1,
                       const int* __restrict__ d2, int e0, int e1, int e2,
                       unsigned* __restrict__ deg, int N) {
    const int g = blockIdx.y;
    const int* dst = (g == 0) ? d0 : (g == 1) ? d1 : d2;
    const int E = (g == 0) ? e0 : (g == 1) ? e1 : e2;
    unsigned* dg = deg + (size_t)g * N;
    int i = blockIdx.x * blockDim.x + threadIdx.x;
    const int stride = gridDim.x * blockDim.x;
    for (; i < E; i += stride) atomicAdd(&dg[dst[i]], 1u);
}

// ---------------- parallel deterministic exclusive scan (3 kernels) ----------------
__global__ __launch_bounds__(256) void k_bsum(const unsigned* __restrict__ deg,
                                              unsigned* __restrict__ bsum, int N) {
    const int g = blockIdx.y, b = blockIdx.x, t = threadIdx.x;
    const unsigned* d = deg + (size_t)g * N;
    const int chunk = (N + gridDim.x - 1) / gridDim.x;
    const int i0 = b * chunk, i1 = min(N, i0 + chunk);
    unsigned s = 0;
    for (int i = i0 + t; i < i1; i += 256) s += d[i];
    __shared__ unsigned red[256];
    red[t] = s;
    __syncthreads();
    for (int ofs = 128; ofs; ofs >>= 1) {
        if (t < ofs) red[t] += red[t + ofs];
        __syncthreads();
    }
    if (t == 0) bsum[g * gridDim.x + b] = red[0];
}

__global__ void k_bscan(unsigned* __restrict__ bsum, int n) {
    const int t = threadIdx.x;
    __shared__ unsigned ps[3 * NB];
    unsigned v = (t < n) ? bsum[t] : 0u;
    ps[t] = v;
    __syncthreads();
    for (int ofs = 1; ofs < NB; ofs <<= 1) {
        const unsigned add = ((t & (NB - 1)) >= ofs) ? ps[t - ofs] : 0u;
        __syncthreads();
        ps[t] += add;
        __syncthreads();
    }
    if (t < n) bsum[t] = ps[t] - v;   // exclusive within each graph segment
}

__global__ __launch_bounds__(256) void k_scan2(const unsigned* __restrict__ deg,
                                               const unsigned* __restrict__ bofs,
                                               int* __restrict__ off, int* __restrict__ cur,
                                               float* __restrict__ rinv, int N) {
    const int g = blockIdx.y, b = blockIdx.x, t = threadIdx.x;
    const unsigned* d = deg + (size_t)g * N;
    int* o = off + (size_t)g * N;
    int* c = cur + (size_t)g * N;
    float* rv = rinv + (size_t)g * N;
    const int chunk = (N + gridDim.x - 1) / gridDim.x;
    const int i0 = b * chunk, i1 = min(N, i0 + chunk);
    unsigned run = bofs[g * gridDim.x + b];
    __shared__ unsigned ps[256];
    for (int base = i0; base < i1; base += 256) {
        const int i = base + t;
        const unsigned v = (i < i1) ? d[i] : 0u;
        ps[t] = v;
        __syncthreads();
        for (int ofs = 1; ofs < 256; ofs <<= 1) {
            const unsigned add = (t >= ofs) ? ps[t - ofs] : 0u;
            __syncthreads();
            ps[t] += add;
            __syncthreads();
        }
        if (i < i1) {
            const unsigned ex = run + ps[t] - v;
            o[i] = (int)ex;
            c[i] = (int)ex;
            rv[i] = 1.0f / ((float)v + 1.0f);
        }
        run += ps[255];
        __syncthreads();
    }
}

// ---------------- fill CSR neighbor lists (3 graphs, blockIdx.y) ----------------
__global__ void k_fill3(const int* __restrict__ s0, const int* __restrict__ d0,
                        const int* __restrict__ s1, const int* __restrict__ d1,
                        const int* __restrict__ s2, const int* __restrict__ d2,
                        int e0, int e1, int e2, int* __restrict__ cur,
                        int* __restrict__ n0, int* __restrict__ n1, int* __restrict__ n2,
                        int N) {
    const int g = blockIdx.y;
    const int* src = (g == 0) ? s0 : (g == 1) ? s1 : s2;
    const int* dst = (g == 0) ? d0 : (g == 1) ? d1 : d2;
    const int E = (g == 0) ? e0 : (g == 1) ? e1 : e2;
    int* nbr = (g == 0) ? n0 : (g == 1) ? n1 : n2;
    int* cu = cur + (size_t)g * N;
    int i = blockIdx.x * blockDim.x + threadIdx.x;
    const int stride = gridDim.x * blockDim.x;
    for (; i < E; i += stride) {
        const int v = dst[i];
        const int p = atomicAdd(&cu[v], 1);
        nbr[p] = src[i];
    }
}

// ---------------- gather (128-dim, 3 graphs via blockIdx.y), BN1 fused ----------------
// AGG3[g][v] = s1 * (rinv_g[v] * (x_v + sum_u x_u)) + sh1
__global__ __launch_bounds__(256) void k_gather3(
    const float* __restrict__ X,
    const int* __restrict__ nbr0, const int* __restrict__ nbr1, const int* __restrict__ nbr2,
    const int* __restrict__ off, const int* __restrict__ cend,
    const float* __restrict__ rinv, const float* __restrict__ s1,
    const float* __restrict__ sh1, float* __restrict__ AGG3, int N) {
    const int g = blockIdx.y;
    const int* nbr = (g == 0) ? nbr0 : (g == 1) ? nbr1 : nbr2;
    const int gb = g * N;
    const int wave = threadIdx.x >> 6;
    const int lane = threadIdx.x & 63;
    const int v = blockIdx.x * 4 + wave;
    if (v >= N) return;
    const int i0 = off[gb + v], i1 = cend[gb + v];
    const int l2 = lane * 2;
    float2 acc = *(const float2*)&X[(size_t)v * FDIM + l2];   // self (raw x)
    int i = i0;
    for (; i + 8 <= i1; i += 8) {
        const int u0 = nbr[i],     u1 = nbr[i + 1], u2 = nbr[i + 2], u3 = nbr[i + 3];
        const int u4 = nbr[i + 4], u5 = nbr[i + 5], u6 = nbr[i + 6], u7 = nbr[i + 7];
        const float2 a0 = *(const float2*)&X[(size_t)u0 * FDIM + l2];
        const float2 a1 = *(const float2*)&X[(size_t)u1 * FDIM + l2];
        const float2 a2 = *(const float2*)&X[(size_t)u2 * FDIM + l2];
        const float2 a3 = *(const float2*)&X[(size_t)u3 * FDIM + l2];
        const float2 a4 = *(const float2*)&X[(size_t)u4 * FDIM + l2];
        const float2 a5 = *(const float2*)&X[(size_t)u5 * FDIM + l2];
        const float2 a6 = *(const float2*)&X[(size_t)u6 * FDIM + l2];
        const float2 a7 = *(const float2*)&X[(size_t)u7 * FDIM + l2];
        acc.x += ((a0.x + a1.x) + (a2.x + a3.x)) + ((a4.x + a5.x) + (a6.x + a7.x));
        acc.y += ((a0.y + a1.y) + (a2.y + a3.y)) + ((a4.y + a5.y) + (a6.y + a7.y));
    }
    for (; i < i1; ++i) {
        const int u = nbr[i];
        const float2 a = *(const float2*)&X[(size_t)u * FDIM + l2];
        acc.x += a.x;
        acc.y += a.y;
    }
    const float r = rinv[gb + v];
    const float2 sc = *(const float2*)&s1[l2];
    const float2 sh = *(const float2*)&sh1[l2];
    float2 o;
    o.x = fmaf(acc.x * r, sc.x, sh.x);
    o.y = fmaf(acc.y * r, sc.y, sh.y);
    *(float2*)&AGG3[((size_t)gb + v) * FDIM + l2] = o;
}

// ---------------- GEMM1: H = relu( [AGG3_0|AGG3_1|AGG3_2] @ [W1;W2;W3] + sum b ), K=384 ----------------
__global__ __launch_bounds__(256) void k_gemm1(
    const float* __restrict__ AGG3,
    const float* __restrict__ W1, const float* __restrict__ W2, const float* __restrict__ W3,
    const float* __restrict__ b1, const float* __restrict__ b2, const float* __restrict__ b3,
    float* __restrict__ H, int N) {
    __shared__ float At[16][64];
    __shared__ float Bt[16][128];
    const int t = threadIdx.x;
    const int row0 = blockIdx.x * 64;
    const int c0 = (t & 31) * 4;     // 0..124
    const int r0 = (t >> 5) * 8;     // 0..56
    float acc[8][4];
    #pragma unroll
    for (int r = 0; r < 8; ++r)
        #pragma unroll
        for (int c = 0; c < 4; ++c) acc[r][c] = 0.f;

    for (int kb = 0; kb < 24; ++kb) {      // K = 384, tiles of 16
        const int g = kb >> 3;
        const int kloc0 = (kb & 7) * 16;
        const float* Ag = AGG3 + (size_t)g * N * FDIM;
        const float* Wg = (g == 0) ? W1 : (g == 1) ? W2 : W3;
        {
            const int kk = t & 15;
            const int rb = t >> 4;          // 0..15
            #pragma unroll
            for (int it = 0; it < 4; ++it) {
                const int r = rb + it * 16;
                const int row = row0 + r;
                At[kk][r] = (row < N) ? Ag[(size_t)row * FDIM + kloc0 + kk] : 0.f;
            }
        }
        {
            const int n = t & 127;
            const int kkb = t >> 7;         // 0..1
            #pragma unroll
            for (int it = 0; it < 8; ++it) {
                const int kk = kkb + it * 2;
                Bt[kk][n] = Wg[(size_t)(kloc0 + kk) * 128 + n];
            }
        }
        __syncthreads();
        #pragma unroll
        for (int kk = 0; kk < 16; ++kk) {
            const float4 b  = *(const float4*)&Bt[kk][c0];
            const float4 a0 = *(const float4*)&At[kk][r0];
            const float4 a1 = *(const float4*)&At[kk][r0 + 4];
            const float a[8] = {a0.x, a0.y, a0.z, a0.w, a1.x, a1.y, a1.z, a1.w};
            #pragma unroll
            for (int r = 0; r < 8; ++r) {
                acc[r][0] = fmaf(a[r], b.x, acc[r][0]);
                acc[r][1] = fmaf(a[r], b.y, acc[r][1]);
                acc[r][2] = fmaf(a[r], b.z, acc[r][2]);
                acc[r][3] = fmaf(a[r], b.w, acc[r][3]);
            }
        }
        __syncthreads();
    }
    float4 base;
    base.x = b1[c0 + 0] + b2[c0 + 0] + b3[c0 + 0];
    base.y = b1[c0 + 1] + b2[c0 + 1] + b3[c0 + 1];
    base.z = b1[c0 + 2] + b2[c0 + 2] + b3[c0 + 2];
    base.w = b1[c0 + 3] + b2[c0 + 3] + b3[c0 + 3];
    #pragma unroll
    for (int r = 0; r < 8; ++r) {
        const int row = row0 + r0 + r;
        if (row < N) {
            float4 o;
            o.x = fmaxf(acc[r][0] + base.x, 0.f);
            o.y = fmaxf(acc[r][1] + base.y, 0.f);
            o.z = fmaxf(acc[r][2] + base.z, 0.f);
            o.w = fmaxf(acc[r][3] + base.w, 0.f);
            *(float4*)&H[(size_t)row * FDIM + c0] = o;
        }
    }
}

// ---------------- c2[g][n] = sum_k sh2[k] * Wg[k][n] (BN2 shift folded through GEMM2) ----------------
__global__ void k_c2(const float* __restrict__ sh2,
                     const float* __restrict__ W1, const float* __restrict__ W2,
                     const float* __restrict__ W3, float* __restrict__ c2) {
    const int t = threadIdx.x;   // 192
    const int g = t >> 6, n = t & 63;
    const float* W = (g == 0) ? W1 : (g == 1) ? W2 : W3;
    float s = 0.f;
    for (int k = 0; k < 128; ++k) s = fmaf(sh2[k], W[(size_t)k * ODIM + n], s);
    c2[g * ODIM + n] = s;
}

// ---------------- GEMM2 (BN2 scale fused into A-load): U_g = (H*s2) @ W_g2 + c2_g ----------------
__global__ __launch_bounds__(256) void k_gemm2(
    const float* __restrict__ H, const float* __restrict__ s2,
    const float* __restrict__ W1, const float* __restrict__ W2, const float* __restrict__ W3,
    const float* __restrict__ c2, float* __restrict__ U, int N) {
    __shared__ float At[16][64];
    __shared__ float Bt[16][64];
    const int t = threadIdx.x;
    const int g = blockIdx.y;
    const int row0 = blockIdx.x * 64;
    const int c0 = (t & 15) * 4;     // 0..60
    const int r0 = (t >> 4) * 4;     // 0..60
    const float* Wg = (g == 0) ? W1 : (g == 1) ? W2 : W3;
    float acc[4][4];
    #pragma unroll
    for (int r = 0; r < 4; ++r)
        #pragma unroll
        for (int c = 0; c < 4; ++c) acc[r][c] = 0.f;

    for (int kb = 0; kb < 8; ++kb) {       // K = 128
        const int k0 = kb * 16;
        {
            const int kk = t & 15;
            const int rb = t >> 4;          // 0..15
            const float sv = s2[k0 + kk];
            #pragma unroll
            for (int it = 0; it < 4; ++it) {
                const int r = rb + it * 16;
                const int row = row0 + r;
                At[kk][r] = (row < N) ? H[(size_t)row * FDIM + k0 + kk] * sv : 0.f;
            }
        }
        {
            const int n = t & 63;
            const int kkb = t >> 6;         // 0..3
            #pragma unroll
            for (int it = 0; it < 4; ++it) {
                const int kk = kkb + it * 4;
                Bt[kk][n] = Wg[(size_t)(k0 + kk) * ODIM + n];
            }
        }
        __syncthreads();
        #pragma unroll
        for (int kk = 0; kk < 16; ++kk) {
            const float4 b = *(const float4*)&Bt[kk][c0];
            const float4 a = *(const float4*)&At[kk][r0];
            const float av[4] = {a.x, a.y, a.z, a.w};
            #pragma unroll
            for (int r = 0; r < 4; ++r) {
                acc[r][0] = fmaf(av[r], b.x, acc[r][0]);
                acc[r][1] = fmaf(av[r], b.y, acc[r][1]);
                acc[r][2] = fmaf(av[r], b.z, acc[r][2]);
                acc[r][3] = fmaf(av[r], b.w, acc[r][3]);
            }
        }
        __syncthreads();
    }
    const float* cg = c2 + (size_t)g * ODIM;
    float* Ug = U + (size_t)g * N * ODIM;
    #pragma unroll
    for (int r = 0; r < 4; ++r) {
        const int row = row0 + r0 + r;
        if (row < N) {
            float4 o;
            o.x = acc[r][0] + cg[c0 + 0];
            o.y = acc[r][1] + cg[c0 + 1];
            o.z = acc[r][2] + cg[c0 + 2];
            o.w = acc[r][3] + cg[c0 + 3];
            *(float4*)&Ug[(size_t)row * ODIM + c0] = o;
        }
    }
}

// ---------------- layer-2 gather + combine ----------------
__global__ __launch_bounds__(256) void k_gc64(
    const float* __restrict__ U,
    const int* __restrict__ nbr0, const int* __restrict__ nbr1, const int* __restrict__ nbr2,
    const int* __restrict__ off, const int* __restrict__ cend,
    const float* __restrict__ rinv,
    const float* __restrict__ b1, const float* __restrict__ b2, const float* __restrict__ b3,
    float* __restrict__ Z, int N) {
    const int wave = threadIdx.x >> 6;
    const int lane = threadIdx.x & 63;
    const int v = blockIdx.x * 4 + wave;
    if (v >= N) return;
    const size_t gs = (size_t)N * ODIM;
    float z = b1[lane] + b2[lane] + b3[lane];
    #pragma unroll
    for (int g = 0; g < 3; ++g) {
        const float* Ug = U + (size_t)g * gs;
        const int* nb = (g == 0) ? nbr0 : (g == 1) ? nbr1 : nbr2;
        const int i0 = off[g * N + v], i1 = cend[g * N + v];
        float s = Ug[(size_t)v * ODIM + lane];
        int i = i0;
        for (; i + 8 <= i1; i += 8) {
            const int u0 = nb[i],     u1 = nb[i + 1], u2 = nb[i + 2], u3 = nb[i + 3];
            const int u4 = nb[i + 4], u5 = nb[i + 5], u6 = nb[i + 6], u7 = nb[i + 7];
            const float a0 = Ug[(size_t)u0 * ODIM + lane];
            const float a1 = Ug[(size_t)u1 * ODIM + lane];
            const float a2 = Ug[(size_t)u2 * ODIM + lane];
            const float a3 = Ug[(size_t)u3 * ODIM + lane];
            const float a4 = Ug[(size_t)u4 * ODIM + lane];
            const float a5 = Ug[(size_t)u5 * ODIM + lane];
            const float a6 = Ug[(size_t)u6 * ODIM + lane];
            const float a7 = Ug[(size_t)u7 * ODIM + lane];
            s += ((a0 + a1) + (a2 + a3)) + ((a4 + a5) + (a6 + a7));
        }
        for (; i < i1; ++i) s += Ug[(size_t)nb[i] * ODIM + lane];
        z += s * rinv[g * N + v];
    }
    Z[(size_t)v * ODIM + lane] = z;
}

// ---------------- final: BN3 + sigmoid + row min-max + row L2, in place ----------------
__global__ __launch_bounds__(256) void k_final(float* __restrict__ Z,
                                               const float* __restrict__ scale,
                                               const float* __restrict__ shift, int N) {
    const int wave = threadIdx.x >> 6;
    const int lane = threadIdx.x & 63;
    const int row = blockIdx.x * 4 + wave;
    if (row >= N) return;
    float v = fmaf(Z[(size_t)row * ODIM + lane], scale[lane], shift[lane]);
    float s = 1.0f / (1.0f + expf(-v));
    float mn = s, mx = s;
    #pragma unroll
    for (int off = 32; off; off >>= 1) {
        mn = fminf(mn, __shfl_xor(mn, off, 64));
        mx = fmaxf(mx, __shfl_xor(mx, off, 64));
    }
    const float sc = (s - mn) / (mx - mn);
    float sq = sc * sc;
    #pragma unroll
    for (int off = 32; off; off >>= 1) sq += __shfl_xor(sq, off, 64);
    const float norm = fmaxf(sqrtf(sq), 1e-12f);
    Z[(size_t)row * ODIM + lane] = sc / norm;
}

extern "C" void kernel_launch(void* const* d_in, const int* in_sizes, int n_in,
                              void* d_out, int out_size, void* d_ws, size_t ws_size,
                              hipStream_t stream) {
    const float* x = (const float*)d_in[0];
    const int* src[3] = {(const int*)d_in[1], (const int*)d_in[3], (const int*)d_in[5]};
    const int* dst[3] = {(const int*)d_in[2], (const int*)d_in[4], (const int*)d_in[6]};
    const int E[3] = {in_sizes[1], in_sizes[3], in_sizes[5]};
    const float* W11 = (const float*)d_in[7];  const float* b11 = (const float*)d_in[8];
    const float* W21 = (const float*)d_in[9];  const float* b21 = (const float*)d_in[10];
    const float* W31 = (const float*)d_in[11]; const float* b31 = (const float*)d_in[12];
    const float* W12 = (const float*)d_in[13]; const float* b12 = (const float*)d_in[14];
    const float* W22 = (const float*)d_in[15]; const float* b22 = (const float*)d_in[16];
    const float* W32 = (const float*)d_in[17]; const float* b32 = (const float*)d_in[18];
    const float* g1  = (const float*)d_in[19]; const float* be1 = (const float*)d_in[20];
    const float* g2  = (const float*)d_in[21]; const float* be2 = (const float*)d_in[22];
    const float* g3  = (const float*)d_in[23]; const float* be3 = (const float*)d_in[24];
    const int N = in_sizes[0] / FDIM;
    float* Z = (float*)d_out;

    // ---- workspace layout (floats) ----
    // H (N*128) | R = AGG3 (3*N*128), U (3*N*64) overlaps AGG3's start (AGG3 dead after gemm1)
    float* ws   = (float*)d_ws;
    float* H    = ws;                          // N*128 (25.6 MB)
    float* AGG3 = H + (size_t)N * FDIM;        // 3*N*128 (76.8 MB)
    float* U    = AGG3;                        // 3*N*64 (38.4 MB), reuses AGG3 region
    float* rinv = AGG3 + (size_t)3 * N * FDIM; // 3N
    float* partial = rinv + (size_t)3 * N;     // 65536
    float* s1  = partial + 65536;  float* sh1 = s1 + 128;
    float* s2  = sh1 + 128;        float* sh2 = s2 + 128;
    float* s3  = sh2 + 128;        float* sh3 = s3 + 64;
    float* c2  = sh3 + 64;                     // 3*64
    // int region
    unsigned* degi  = (unsigned*)(c2 + 3 * ODIM);         // 3N
    unsigned* bsum  = degi + (size_t)3 * N;               // 3*NB
    int* off  = (int*)(bsum + (size_t)3 * NB);            // 3N
    int* cur  = off + (size_t)3 * N;                      // 3N
    int* nbr  = cur + (size_t)3 * N;                      // E0+E1+E2
    int* nbrg[3];
    nbrg[0] = nbr;
    nbrg[1] = nbrg[0] + E[0];
    nbrg[2] = nbrg[1] + E[1];

    // ---- degrees + CSR build (deterministic parallel scan for offsets) ----
    hipMemsetAsync(degi, 0, (size_t)3 * N * sizeof(unsigned), stream);
    k_deg3<<<dim3(1024, 3), 256, 0, stream>>>(dst[0], dst[1], dst[2], E[0], E[1], E[2], degi, N);
    k_bsum<<<dim3(NB, 3), 256, 0, stream>>>(degi, bsum, N);
    k_bscan<<<1, 3 * NB, 0, stream>>>(bsum, 3 * NB);
    k_scan2<<<dim3(NB, 3), 256, 0, stream>>>(degi, bsum, off, cur, rinv, N);
    k_fill3<<<dim3(2048, 3), 256, 0, stream>>>(src[0], dst[0], src[1], dst[1], src[2], dst[2],
                                               E[0], E[1], E[2], cur,
                                               nbrg[0], nbrg[1], nbrg[2], N);

    // ---- BN1 stats (applied inside gather epilogue) ----
    k_colstats<128><<<256, 128, 0, stream>>>(x, N, partial);
    k_colstats_fin<128><<<1, 128, 0, stream>>>(partial, 256, N, g1, be1, s1, sh1);

    // ---- layer 1: 3-graph gather (one dispatch) -> single K=384 GEMM ----
    const int gblocks = (N + 3) / 4;
    k_gather3<<<dim3(gblocks, 3), 256, 0, stream>>>(x, nbrg[0], nbrg[1], nbrg[2],
                                                    off, cur, rinv, s1, sh1, AGG3, N);
    k_gemm1<<<(N + 63) / 64, 256, 0, stream>>>(AGG3, W11, W21, W31, b11, b21, b31, H, N);

    // ---- BN2 stats (scale fused into GEMM2 A-load, shift folded via c2) ----
    k_colstats<128><<<256, 128, 0, stream>>>(H, N, partial);
    k_colstats_fin<128><<<1, 128, 0, stream>>>(partial, 256, N, g2, be2, s2, sh2);
    k_c2<<<1, 192, 0, stream>>>(sh2, W12, W22, W32, c2);

    // ---- layer 2: GEMM first (linearity; writes U over dead AGG3), then gather+combine ----
    dim3 grid2((N + 63) / 64, 3);
    k_gemm2<<<grid2, 256, 0, stream>>>(H, s2, W12, W22, W32, c2, U, N);
    k_gc64<<<gblocks, 256, 0, stream>>>(U, nbrg[0], nbrg[1], nbrg[2], off, cur, rinv,
                                        b12, b22, b32, Z, N);

    // ---- BN3 + epilogue ----
    k_colstats<64><<<256, 64, 0, stream>>>(Z, N, partial);
    k_colstats_fin<64><<<1, 64, 0, stream>>>(partial, 256, N, g3, be3, s3, sh3);
    k_final<<<(N + 3) / 4, 256, 0, stream>>>(Z, s3, sh3, N);
}

// Round 8
// 996.100 us; speedup vs baseline: 1.2157x; 1.0712x over previous
//
#include <hip/hip_runtime.h>
#include <math.h>

constexpr int FDIM = 128;   // IN == HID
constexpr int ODIM = 64;    // NC
constexpr int NB   = 256;   // scan blocks per graph

// bf16 helpers (RNE pack, bit-shift unpack)
__device__ inline unsigned short f2bf(float f) {
    unsigned u = __float_as_uint(f);
    u = (u + 0x7fffu + ((u >> 16) & 1u)) >> 16;
    return (unsigned short)u;
}
__device__ inline float bf2f(unsigned short s) { return __uint_as_float(((unsigned)s) << 16); }
__device__ inline float blo(unsigned v) { return __uint_as_float(v << 16); }
__device__ inline float bhi(unsigned v) { return __uint_as_float(v & 0xffff0000u); }

// ---------------- column stats (deterministic two-stage) ----------------
template<int C>
__global__ void k_colstats(const float* __restrict__ X, int N, float* __restrict__ partial) {
    const int c = threadIdx.x;          // blockDim.x == C
    const int nb = gridDim.x;
    const int rows_per = (N + nb - 1) / nb;
    const int r0 = blockIdx.x * rows_per;
    const int r1 = min(N, r0 + rows_per);
    float s = 0.f, ss = 0.f;
    for (int r = r0; r < r1; ++r) {
        float v = X[(size_t)r * C + c];
        s += v;
        ss += v * v;
    }
    partial[(size_t)blockIdx.x * (2 * C) + c]     = s;
    partial[(size_t)blockIdx.x * (2 * C) + C + c] = ss;
}

template<int C>
__global__ void k_colstats_fin(const float* __restrict__ partial, int nb, int N,
                               const float* __restrict__ gamma, const float* __restrict__ beta,
                               float* __restrict__ scale, float* __restrict__ shift) {
    const int c = threadIdx.x;          // blockDim.x == C
    float s = 0.f, ss = 0.f;
    for (int b = 0; b < nb; ++b) {
        s  += partial[(size_t)b * (2 * C) + c];
        ss += partial[(size_t)b * (2 * C) + C + c];
    }
    const float mu  = s / (float)N;
    const float var = ss / (float)N - mu * mu;
    const float sc  = gamma[c] * rsqrtf(var + 1e-5f);
    scale[c] = sc;
    shift[c] = beta[c] - mu * sc;
}

// ---------------- f32 -> bf16 conversion (8 elems/thread) ----------------
__global__ void k_cvt(const float* __restrict__ X, unsigned short* __restrict__ XB, size_t n8) {
    for (size_t i = (size_t)blockIdx.x * blockDim.x + threadIdx.x; i < n8;
         i += (size_t)gridDim.x * blockDim.x) {
        const float4 a = ((const float4*)X)[2 * i];
        const float4 b = ((const float4*)X)[2 * i + 1];
        uint4 o;
        o.x = (unsigned)f2bf(a.x) | ((unsigned)f2bf(a.y) << 16);
        o.y = (unsigned)f2bf(a.z) | ((unsigned)f2bf(a.w) << 16);
        o.z = (unsigned)f2bf(b.x) | ((unsigned)f2bf(b.y) << 16);
        o.w = (unsigned)f2bf(b.z) | ((unsigned)f2bf(b.w) << 16);
        ((uint4*)XB)[i] = o;
    }
}

// ---------------- degree (3 graphs, blockIdx.y) ----------------
__global__ void k_deg3(const int* __restrict__ d0, const int* __restrict__ d1,
                       const int* __restrict__ d2, int e0, int e1, int e2,
                       unsigned* __restrict__ deg, int N) {
    const int g = blockIdx.y;
    const int* dst = (g == 0) ? d0 : (g == 1) ? d1 : d2;
    const int E = (g == 0) ? e0 : (g == 1) ? e1 : e2;
    unsigned* dg = deg + (size_t)g * N;
    int i = blockIdx.x * blockDim.x + threadIdx.x;
    const int stride = gridDim.x * blockDim.x;
    for (; i < E; i += stride) atomicAdd(&dg[dst[i]], 1u);
}

// ---------------- parallel deterministic exclusive scan (3 kernels) ----------------
__global__ __launch_bounds__(256) void k_bsum(const unsigned* __restrict__ deg,
                                              unsigned* __restrict__ bsum, int N) {
    const int g = blockIdx.y, b = blockIdx.x, t = threadIdx.x;
    const unsigned* d = deg + (size_t)g * N;
    const int chunk = (N + gridDim.x - 1) / gridDim.x;
    const int i0 = b * chunk, i1 = min(N, i0 + chunk);
    unsigned s = 0;
    for (int i = i0 + t; i < i1; i += 256) s += d[i];
    __shared__ unsigned red[256];
    red[t] = s;
    __syncthreads();
    for (int ofs = 128; ofs; ofs >>= 1) {
        if (t < ofs) red[t] += red[t + ofs];
        __syncthreads();
    }
    if (t == 0) bsum[g * gridDim.x + b] = red[0];
}

__global__ void k_bscan(unsigned* __restrict__ bsum, int n) {
    const int t = threadIdx.x;
    __shared__ unsigned ps[3 * NB];
    unsigned v = (t < n) ? bsum[t] : 0u;
    ps[t] = v;
    __syncthreads();
    for (int ofs = 1; ofs < NB; ofs <<= 1) {
        const unsigned add = ((t & (NB - 1)) >= ofs) ? ps[t - ofs] : 0u;
        __syncthreads();
        ps[t] += add;
        __syncthreads();
    }
    if (t < n) bsum[t] = ps[t] - v;   // exclusive within each graph segment
}

__global__ __launch_bounds__(256) void k_scan2(const unsigned* __restrict__ deg,
                                               const unsigned* __restrict__ bofs,
                                               int* __restrict__ off, int* __restrict__ cur,
                                               float* __restrict__ rinv, int N) {
    const int g = blockIdx.y, b = blockIdx.x, t = threadIdx.x;
    const unsigned* d = deg + (size_t)g * N;
    int* o = off + (size_t)g * N;
    int* c = cur + (size_t)g * N;
    float* rv = rinv + (size_t)g * N;
    const int chunk = (N + gridDim.x - 1) / gridDim.x;
    const int i0 = b * chunk, i1 = min(N, i0 + chunk);
    unsigned run = bofs[g * gridDim.x + b];
    __shared__ unsigned ps[256];
    for (int base = i0; base < i1; base += 256) {
        const int i = base + t;
        const unsigned v = (i < i1) ? d[i] : 0u;
        ps[t] = v;
        __syncthreads();
        for (int ofs = 1; ofs < 256; ofs <<= 1) {
            const unsigned add = (t >= ofs) ? ps[t - ofs] : 0u;
            __syncthreads();
            ps[t] += add;
            __syncthreads();
        }
        if (i < i1) {
            const unsigned ex = run + ps[t] - v;
            o[i] = (int)ex;
            c[i] = (int)ex;
            rv[i] = 1.0f / ((float)v + 1.0f);
        }
        run += ps[255];
        __syncthreads();
    }
}

// ---------------- fill CSR neighbor lists (3 graphs, blockIdx.y) ----------------
__global__ void k_fill3(const int* __restrict__ s0, const int* __restrict__ d0,
                        const int* __restrict__ s1, const int* __restrict__ d1,
                        const int* __restrict__ s2, const int* __restrict__ d2,
                        int e0, int e1, int e2, int* __restrict__ cur,
                        int* __restrict__ n0, int* __restrict__ n1, int* __restrict__ n2,
                        int N) {
    const int g = blockIdx.y;
    const int* src = (g == 0) ? s0 : (g == 1) ? s1 : s2;
    const int* dst = (g == 0) ? d0 : (g == 1) ? d1 : d2;
    const int E = (g == 0) ? e0 : (g == 1) ? e1 : e2;
    int* nbr = (g == 0) ? n0 : (g == 1) ? n1 : n2;
    int* cu = cur + (size_t)g * N;
    int i = blockIdx.x * blockDim.x + threadIdx.x;
    const int stride = gridDim.x * blockDim.x;
    for (; i < E; i += stride) {
        const int v = dst[i];
        const int p = atomicAdd(&cu[v], 1);
        nbr[p] = src[i];
    }
}

// ---------------- gather (bf16 x rows, 3 graphs via blockIdx.y), BN1 fused ----------------
// AGG3[g][v] = s1 * (rinv_g[v] * (xb_v + sum_u xb_u)) + sh1   (f32 accumulate/output)
__global__ __launch_bounds__(256) void k_gather3(
    const unsigned short* __restrict__ XB,
    const int* __restrict__ nbr0, const int* __restrict__ nbr1, const int* __restrict__ nbr2,
    const int* __restrict__ off, const int* __restrict__ cend,
    const float* __restrict__ rinv, const float* __restrict__ s1,
    const float* __restrict__ sh1, float* __restrict__ AGG3, int N) {
    const int g = blockIdx.y;
    const int* nbr = (g == 0) ? nbr0 : (g == 1) ? nbr1 : nbr2;
    const int gb = g * N;
    const int wave = threadIdx.x >> 6;
    const int lane = threadIdx.x & 63;
    const int v = blockIdx.x * 4 + wave;
    if (v >= N) return;
    const int i0 = off[gb + v], i1 = cend[gb + v];
    const int l2 = lane * 2;
    // self term
    unsigned sv = ((const unsigned*)(XB + (size_t)v * FDIM))[lane];
    float2 acc;
    acc.x = blo(sv);
    acc.y = bhi(sv);
    int i = i0;
    for (; i + 8 <= i1; i += 8) {
        const int u0 = nbr[i],     u1 = nbr[i + 1], u2 = nbr[i + 2], u3 = nbr[i + 3];
        const int u4 = nbr[i + 4], u5 = nbr[i + 5], u6 = nbr[i + 6], u7 = nbr[i + 7];
        const unsigned a0 = ((const unsigned*)(XB + (size_t)u0 * FDIM))[lane];
        const unsigned a1 = ((const unsigned*)(XB + (size_t)u1 * FDIM))[lane];
        const unsigned a2 = ((const unsigned*)(XB + (size_t)u2 * FDIM))[lane];
        const unsigned a3 = ((const unsigned*)(XB + (size_t)u3 * FDIM))[lane];
        const unsigned a4 = ((const unsigned*)(XB + (size_t)u4 * FDIM))[lane];
        const unsigned a5 = ((const unsigned*)(XB + (size_t)u5 * FDIM))[lane];
        const unsigned a6 = ((const unsigned*)(XB + (size_t)u6 * FDIM))[lane];
        const unsigned a7 = ((const unsigned*)(XB + (size_t)u7 * FDIM))[lane];
        acc.x += ((blo(a0) + blo(a1)) + (blo(a2) + blo(a3))) + ((blo(a4) + blo(a5)) + (blo(a6) + blo(a7)));
        acc.y += ((bhi(a0) + bhi(a1)) + (bhi(a2) + bhi(a3))) + ((bhi(a4) + bhi(a5)) + (bhi(a6) + bhi(a7)));
    }
    for (; i < i1; ++i) {
        const unsigned a = ((const unsigned*)(XB + (size_t)nbr[i] * FDIM))[lane];
        acc.x += blo(a);
        acc.y += bhi(a);
    }
    const float r = rinv[gb + v];
    const float2 sc = *(const float2*)&s1[l2];
    const float2 sh = *(const float2*)&sh1[l2];
    float2 o;
    o.x = fmaf(acc.x * r, sc.x, sh.x);
    o.y = fmaf(acc.y * r, sc.y, sh.y);
    *(float2*)&AGG3[((size_t)gb + v) * FDIM + l2] = o;
}

// ---------------- GEMM1: H = relu( [AGG3_0|AGG3_1|AGG3_2] @ [W1;W2;W3] + sum b ), K=384 ----------------
__global__ __launch_bounds__(256) void k_gemm1(
    const float* __restrict__ AGG3,
    const float* __restrict__ W1, const float* __restrict__ W2, const float* __restrict__ W3,
    const float* __restrict__ b1, const float* __restrict__ b2, const float* __restrict__ b3,
    float* __restrict__ H, int N) {
    __shared__ float At[16][64];
    __shared__ float Bt[16][128];
    const int t = threadIdx.x;
    const int row0 = blockIdx.x * 64;
    const int c0 = (t & 31) * 4;     // 0..124
    const int r0 = (t >> 5) * 8;     // 0..56
    float acc[8][4];
    #pragma unroll
    for (int r = 0; r < 8; ++r)
        #pragma unroll
        for (int c = 0; c < 4; ++c) acc[r][c] = 0.f;

    for (int kb = 0; kb < 24; ++kb) {      // K = 384, tiles of 16
        const int g = kb >> 3;
        const int kloc0 = (kb & 7) * 16;
        const float* Ag = AGG3 + (size_t)g * N * FDIM;
        const float* Wg = (g == 0) ? W1 : (g == 1) ? W2 : W3;
        {
            const int kk = t & 15;
            const int rb = t >> 4;          // 0..15
            #pragma unroll
            for (int it = 0; it < 4; ++it) {
                const int r = rb + it * 16;
                const int row = row0 + r;
                At[kk][r] = (row < N) ? Ag[(size_t)row * FDIM + kloc0 + kk] : 0.f;
            }
        }
        {
            const int n = t & 127;
            const int kkb = t >> 7;         // 0..1
            #pragma unroll
            for (int it = 0; it < 8; ++it) {
                const int kk = kkb + it * 2;
                Bt[kk][n] = Wg[(size_t)(kloc0 + kk) * 128 + n];
            }
        }
        __syncthreads();
        #pragma unroll
        for (int kk = 0; kk < 16; ++kk) {
            const float4 b  = *(const float4*)&Bt[kk][c0];
            const float4 a0 = *(const float4*)&At[kk][r0];
            const float4 a1 = *(const float4*)&At[kk][r0 + 4];
            const float a[8] = {a0.x, a0.y, a0.z, a0.w, a1.x, a1.y, a1.z, a1.w};
            #pragma unroll
            for (int r = 0; r < 8; ++r) {
                acc[r][0] = fmaf(a[r], b.x, acc[r][0]);
                acc[r][1] = fmaf(a[r], b.y, acc[r][1]);
                acc[r][2] = fmaf(a[r], b.z, acc[r][2]);
                acc[r][3] = fmaf(a[r], b.w, acc[r][3]);
            }
        }
        __syncthreads();
    }
    float4 base;
    base.x = b1[c0 + 0] + b2[c0 + 0] + b3[c0 + 0];
    base.y = b1[c0 + 1] + b2[c0 + 1] + b3[c0 + 1];
    base.z = b1[c0 + 2] + b2[c0 + 2] + b3[c0 + 2];
    base.w = b1[c0 + 3] + b2[c0 + 3] + b3[c0 + 3];
    #pragma unroll
    for (int r = 0; r < 8; ++r) {
        const int row = row0 + r0 + r;
        if (row < N) {
            float4 o;
            o.x = fmaxf(acc[r][0] + base.x, 0.f);
            o.y = fmaxf(acc[r][1] + base.y, 0.f);
            o.z = fmaxf(acc[r][2] + base.z, 0.f);
            o.w = fmaxf(acc[r][3] + base.w, 0.f);
            *(float4*)&H[(size_t)row * FDIM + c0] = o;
        }
    }
}

// ---------------- c2[g][n] = sum_k sh2[k] * Wg[k][n] (BN2 shift folded through GEMM2) ----------------
__global__ void k_c2(const float* __restrict__ sh2,
                     const float* __restrict__ W1, const float* __restrict__ W2,
                     const float* __restrict__ W3, float* __restrict__ c2) {
    const int t = threadIdx.x;   // 192
    const int g = t >> 6, n = t & 63;
    const float* W = (g == 0) ? W1 : (g == 1) ? W2 : W3;
    float s = 0.f;
    for (int k = 0; k < 128; ++k) s = fmaf(sh2[k], W[(size_t)k * ODIM + n], s);
    c2[g * ODIM + n] = s;
}

// ---------------- GEMM2 (BN2 scale fused): U_g = bf16( (H*s2) @ W_g2 + c2_g ) ----------------
__global__ __launch_bounds__(256) void k_gemm2(
    const float* __restrict__ H, const float* __restrict__ s2,
    const float* __restrict__ W1, const float* __restrict__ W2, const float* __restrict__ W3,
    const float* __restrict__ c2, unsigned short* __restrict__ Ub, int N) {
    __shared__ float At[16][64];
    __shared__ float Bt[16][64];
    const int t = threadIdx.x;
    const int g = blockIdx.y;
    const int row0 = blockIdx.x * 64;
    const int c0 = (t & 15) * 4;     // 0..60
    const int r0 = (t >> 4) * 4;     // 0..60
    const float* Wg = (g == 0) ? W1 : (g == 1) ? W2 : W3;
    float acc[4][4];
    #pragma unroll
    for (int r = 0; r < 4; ++r)
        #pragma unroll
        for (int c = 0; c < 4; ++c) acc[r][c] = 0.f;

    for (int kb = 0; kb < 8; ++kb) {       // K = 128
        const int k0 = kb * 16;
        {
            const int kk = t & 15;
            const int rb = t >> 4;          // 0..15
            const float sv = s2[k0 + kk];
            #pragma unroll
            for (int it = 0; it < 4; ++it) {
                const int r = rb + it * 16;
                const int row = row0 + r;
                At[kk][r] = (row < N) ? H[(size_t)row * FDIM + k0 + kk] * sv : 0.f;
            }
        }
        {
            const int n = t & 63;
            const int kkb = t >> 6;         // 0..3
            #pragma unroll
            for (int it = 0; it < 4; ++it) {
                const int kk = kkb + it * 4;
                Bt[kk][n] = Wg[(size_t)(k0 + kk) * ODIM + n];
            }
        }
        __syncthreads();
        #pragma unroll
        for (int kk = 0; kk < 16; ++kk) {
            const float4 b = *(const float4*)&Bt[kk][c0];
            const float4 a = *(const float4*)&At[kk][r0];
            const float av[4] = {a.x, a.y, a.z, a.w};
            #pragma unroll
            for (int r = 0; r < 4; ++r) {
                acc[r][0] = fmaf(av[r], b.x, acc[r][0]);
                acc[r][1] = fmaf(av[r], b.y, acc[r][1]);
                acc[r][2] = fmaf(av[r], b.z, acc[r][2]);
                acc[r][3] = fmaf(av[r], b.w, acc[r][3]);
            }
        }
        __syncthreads();
    }
    const float* cg = c2 + (size_t)g * ODIM;
    unsigned short* Ug = Ub + (size_t)g * N * ODIM;
    #pragma unroll
    for (int r = 0; r < 4; ++r) {
        const int row = row0 + r0 + r;
        if (row < N) {
            uint2 w;
            w.x = (unsigned)f2bf(acc[r][0] + cg[c0 + 0]) | ((unsigned)f2bf(acc[r][1] + cg[c0 + 1]) << 16);
            w.y = (unsigned)f2bf(acc[r][2] + cg[c0 + 2]) | ((unsigned)f2bf(acc[r][3] + cg[c0 + 3]) << 16);
            *(uint2*)&Ug[(size_t)row * ODIM + c0] = w;
        }
    }
}

// ---------------- layer-2 gather + combine (bf16 U rows) ----------------
__global__ __launch_bounds__(256) void k_gc64(
    const unsigned short* __restrict__ Ub,
    const int* __restrict__ nbr0, const int* __restrict__ nbr1, const int* __restrict__ nbr2,
    const int* __restrict__ off, const int* __restrict__ cend,
    const float* __restrict__ rinv,
    const float* __restrict__ b1, const float* __restrict__ b2, const float* __restrict__ b3,
    float* __restrict__ Z, int N) {
    const int wave = threadIdx.x >> 6;
    const int lane = threadIdx.x & 63;
    const int v = blockIdx.x * 4 + wave;
    if (v >= N) return;
    const size_t gs = (size_t)N * ODIM;
    float z = b1[lane] + b2[lane] + b3[lane];
    #pragma unroll
    for (int g = 0; g < 3; ++g) {
        const unsigned short* Ug = Ub + (size_t)g * gs;
        const int* nb = (g == 0) ? nbr0 : (g == 1) ? nbr1 : nbr2;
        const int i0 = off[g * N + v], i1 = cend[g * N + v];
        float s = bf2f(Ug[(size_t)v * ODIM + lane]);
        int i = i0;
        for (; i + 8 <= i1; i += 8) {
            const int u0 = nb[i],     u1 = nb[i + 1], u2 = nb[i + 2], u3 = nb[i + 3];
            const int u4 = nb[i + 4], u5 = nb[i + 5], u6 = nb[i + 6], u7 = nb[i + 7];
            const float a0 = bf2f(Ug[(size_t)u0 * ODIM + lane]);
            const float a1 = bf2f(Ug[(size_t)u1 * ODIM + lane]);
            const float a2 = bf2f(Ug[(size_t)u2 * ODIM + lane]);
            const float a3 = bf2f(Ug[(size_t)u3 * ODIM + lane]);
            const float a4 = bf2f(Ug[(size_t)u4 * ODIM + lane]);
            const float a5 = bf2f(Ug[(size_t)u5 * ODIM + lane]);
            const float a6 = bf2f(Ug[(size_t)u6 * ODIM + lane]);
            const float a7 = bf2f(Ug[(size_t)u7 * ODIM + lane]);
            s += ((a0 + a1) + (a2 + a3)) + ((a4 + a5) + (a6 + a7));
        }
        for (; i < i1; ++i) s += bf2f(Ug[(size_t)nb[i] * ODIM + lane]);
        z += s * rinv[g * N + v];
    }
    Z[(size_t)v * ODIM + lane] = z;
}

// ---------------- final: BN3 + sigmoid + row min-max + row L2, in place ----------------
__global__ __launch_bounds__(256) void k_final(float* __restrict__ Z,
                                               const float* __restrict__ scale,
                                               const float* __restrict__ shift, int N) {
    const int wave = threadIdx.x >> 6;
    const int lane = threadIdx.x & 63;
    const int row = blockIdx.x * 4 + wave;
    if (row >= N) return;
    float v = fmaf(Z[(size_t)row * ODIM + lane], scale[lane], shift[lane]);
    float s = 1.0f / (1.0f + expf(-v));
    float mn = s, mx = s;
    #pragma unroll
    for (int off = 32; off; off >>= 1) {
        mn = fminf(mn, __shfl_xor(mn, off, 64));
        mx = fmaxf(mx, __shfl_xor(mx, off, 64));
    }
    const float sc = (s - mn) / (mx - mn);
    float sq = sc * sc;
    #pragma unroll
    for (int off = 32; off; off >>= 1) sq += __shfl_xor(sq, off, 64);
    const float norm = fmaxf(sqrtf(sq), 1e-12f);
    Z[(size_t)row * ODIM + lane] = sc / norm;
}

extern "C" void kernel_launch(void* const* d_in, const int* in_sizes, int n_in,
                              void* d_out, int out_size, void* d_ws, size_t ws_size,
                              hipStream_t stream) {
    const float* x = (const float*)d_in[0];
    const int* src[3] = {(const int*)d_in[1], (const int*)d_in[3], (const int*)d_in[5]};
    const int* dst[3] = {(const int*)d_in[2], (const int*)d_in[4], (const int*)d_in[6]};
    const int E[3] = {in_sizes[1], in_sizes[3], in_sizes[5]};
    const float* W11 = (const float*)d_in[7];  const float* b11 = (const float*)d_in[8];
    const float* W21 = (const float*)d_in[9];  const float* b21 = (const float*)d_in[10];
    const float* W31 = (const float*)d_in[11]; const float* b31 = (const float*)d_in[12];
    const float* W12 = (const float*)d_in[13]; const float* b12 = (const float*)d_in[14];
    const float* W22 = (const float*)d_in[15]; const float* b22 = (const float*)d_in[16];
    const float* W32 = (const float*)d_in[17]; const float* b32 = (const float*)d_in[18];
    const float* g1  = (const float*)d_in[19]; const float* be1 = (const float*)d_in[20];
    const float* g2  = (const float*)d_in[21]; const float* be2 = (const float*)d_in[22];
    const float* g3  = (const float*)d_in[23]; const float* be3 = (const float*)d_in[24];
    const int N = in_sizes[0] / FDIM;
    float* Z = (float*)d_out;

    // ---- workspace layout (floats) ----
    // H (N*128 f32) | AGG3 (3*N*128 f32) | tails
    // xb (bf16 N*128 = 12.8MB) aliases H (dead before gemm1 writes H)
    // Ub (bf16 3*N*64 = 19.2MB) aliases AGG3 (AGG3 dead after gemm1)
    float* ws   = (float*)d_ws;
    float* H    = ws;                          // N*128 (25.6 MB)
    unsigned short* xb = (unsigned short*)H;   // bf16 N*128, aliases H
    float* AGG3 = H + (size_t)N * FDIM;        // 3*N*128 (76.8 MB)
    unsigned short* Ub = (unsigned short*)AGG3;// bf16 3*N*64, aliases AGG3
    float* rinv = AGG3 + (size_t)3 * N * FDIM; // 3N
    float* partial = rinv + (size_t)3 * N;     // 65536
    float* s1  = partial + 65536;  float* sh1 = s1 + 128;
    float* s2  = sh1 + 128;        float* sh2 = s2 + 128;
    float* s3  = sh2 + 128;        float* sh3 = s3 + 64;
    float* c2  = sh3 + 64;                     // 3*64
    // int region
    unsigned* degi  = (unsigned*)(c2 + 3 * ODIM);         // 3N
    unsigned* bsum  = degi + (size_t)3 * N;               // 3*NB
    int* off  = (int*)(bsum + (size_t)3 * NB);            // 3N
    int* cur  = off + (size_t)3 * N;                      // 3N
    int* nbr  = cur + (size_t)3 * N;                      // E0+E1+E2
    int* nbrg[3];
    nbrg[0] = nbr;
    nbrg[1] = nbrg[0] + E[0];
    nbrg[2] = nbrg[1] + E[1];

    // ---- degrees + CSR build (deterministic parallel scan for offsets) ----
    hipMemsetAsync(degi, 0, (size_t)3 * N * sizeof(unsigned), stream);
    k_deg3<<<dim3(1024, 3), 256, 0, stream>>>(dst[0], dst[1], dst[2], E[0], E[1], E[2], degi, N);
    k_bsum<<<dim3(NB, 3), 256, 0, stream>>>(degi, bsum, N);
    k_bscan<<<1, 3 * NB, 0, stream>>>(bsum, 3 * NB);
    k_scan2<<<dim3(NB, 3), 256, 0, stream>>>(degi, bsum, off, cur, rinv, N);
    k_fill3<<<dim3(2048, 3), 256, 0, stream>>>(src[0], dst[0], src[1], dst[1], src[2], dst[2],
                                               E[0], E[1], E[2], cur,
                                               nbrg[0], nbrg[1], nbrg[2], N);

    // ---- BN1 stats (f32 x) + bf16 conversion of x ----
    k_colstats<128><<<256, 128, 0, stream>>>(x, N, partial);
    k_colstats_fin<128><<<1, 128, 0, stream>>>(partial, 256, N, g1, be1, s1, sh1);
    k_cvt<<<1024, 256, 0, stream>>>(x, xb, (size_t)N * FDIM / 8);

    // ---- layer 1: 3-graph bf16 gather (one dispatch) -> single K=384 GEMM ----
    const int gblocks = (N + 3) / 4;
    k_gather3<<<dim3(gblocks, 3), 256, 0, stream>>>(xb, nbrg[0], nbrg[1], nbrg[2],
                                                    off, cur, rinv, s1, sh1, AGG3, N);
    k_gemm1<<<(N + 63) / 64, 256, 0, stream>>>(AGG3, W11, W21, W31, b11, b21, b31, H, N);

    // ---- BN2 stats (scale fused into GEMM2 A-load, shift folded via c2) ----
    k_colstats<128><<<256, 128, 0, stream>>>(H, N, partial);
    k_colstats_fin<128><<<1, 128, 0, stream>>>(partial, 256, N, g2, be2, s2, sh2);
    k_c2<<<1, 192, 0, stream>>>(sh2, W12, W22, W32, c2);

    // ---- layer 2: GEMM first (bf16 U over dead AGG3), then bf16 gather+combine ----
    dim3 grid2((N + 63) / 64, 3);
    k_gemm2<<<grid2, 256, 0, stream>>>(H, s2, W12, W22, W32, c2, Ub, N);
    k_gc64<<<gblocks, 256, 0, stream>>>(Ub, nbrg[0], nbrg[1], nbrg[2], off, cur, rinv,
                                        b12, b22, b32, Z, N);

    // ---- BN3 + epilogue ----
    k_colstats<64><<<256, 64, 0, stream>>>(Z, N, partial);
    k_colstats_fin<64><<<1, 64, 0, stream>>>(partial, 256, N, g3, be3, s3, sh3);
    k_final<<<(N + 3) / 4, 256, 0, stream>>>(Z, s3, sh3, N);
}

// Round 9
// 762.079 us; speedup vs baseline: 1.5891x; 1.3071x over previous
//
#include <hip/hip_runtime.h>
#include <math.h>

constexpr int FDIM = 128;   // IN == HID
constexpr int ODIM = 64;    // NC
constexpr int BINB = 512;   // binning blocks per graph
constexpr int NBK  = 256;   // max buckets (256 nodes each -> N <= 65536)

// bf16 helpers (RNE pack, bit-shift unpack)
__device__ inline unsigned short f2bf(float f) {
    unsigned u = __float_as_uint(f);
    u = (u + 0x7fffu + ((u >> 16) & 1u)) >> 16;
    return (unsigned short)u;
}
__device__ inline float bf2f(unsigned short s) { return __uint_as_float(((unsigned)s) << 16); }
__device__ inline float blo(unsigned v) { return __uint_as_float(v << 16); }
__device__ inline float bhi(unsigned v) { return __uint_as_float(v & 0xffff0000u); }

// ---------------- column stats (deterministic two-stage) ----------------
template<int C>
__global__ void k_colstats(const float* __restrict__ X, int N, float* __restrict__ partial) {
    const int c = threadIdx.x;          // blockDim.x == C
    const int nb = gridDim.x;
    const int rows_per = (N + nb - 1) / nb;
    const int r0 = blockIdx.x * rows_per;
    const int r1 = min(N, r0 + rows_per);
    float s = 0.f, ss = 0.f;
    for (int r = r0; r < r1; ++r) {
        float v = X[(size_t)r * C + c];
        s += v;
        ss += v * v;
    }
    partial[(size_t)blockIdx.x * (2 * C) + c]     = s;
    partial[(size_t)blockIdx.x * (2 * C) + C + c] = ss;
}

template<int C>
__global__ void k_colstats_fin(const float* __restrict__ partial, int nb, int N,
                               const float* __restrict__ gamma, const float* __restrict__ beta,
                               float* __restrict__ scale, float* __restrict__ shift) {
    const int c = threadIdx.x;          // blockDim.x == C
    float s = 0.f, ss = 0.f;
    for (int b = 0; b < nb; ++b) {
        s  += partial[(size_t)b * (2 * C) + c];
        ss += partial[(size_t)b * (2 * C) + C + c];
    }
    const float mu  = s / (float)N;
    const float var = ss / (float)N - mu * mu;
    const float sc  = gamma[c] * rsqrtf(var + 1e-5f);
    scale[c] = sc;
    shift[c] = beta[c] - mu * sc;
}

// ---------------- f32 -> bf16 conversion (8 elems/thread) ----------------
__global__ void k_cvt(const float* __restrict__ X, unsigned short* __restrict__ XB, size_t n8) {
    for (size_t i = (size_t)blockIdx.x * blockDim.x + threadIdx.x; i < n8;
         i += (size_t)gridDim.x * blockDim.x) {
        const float4 a = ((const float4*)X)[2 * i];
        const float4 b = ((const float4*)X)[2 * i + 1];
        uint4 o;
        o.x = (unsigned)f2bf(a.x) | ((unsigned)f2bf(a.y) << 16);
        o.y = (unsigned)f2bf(a.z) | ((unsigned)f2bf(a.w) << 16);
        o.z = (unsigned)f2bf(b.x) | ((unsigned)f2bf(b.y) << 16);
        o.w = (unsigned)f2bf(b.z) | ((unsigned)f2bf(b.w) << 16);
        ((uint4*)XB)[i] = o;
    }
}

// ================= CSR build via bucket binning (single-writer nbr lines) =================
// bucket of node v = v >> 8 (256 nodes per bucket). cnts layout: [g][bucket][block] (3*NBK*BINB).

// (1) per-block bucket histograms
__global__ __launch_bounds__(256) void k_bincount(
    const int* __restrict__ d0, const int* __restrict__ d1, const int* __restrict__ d2,
    int e0, int e1, int e2, unsigned* __restrict__ cnts) {
    const int g = blockIdx.y, blk = blockIdx.x, t = threadIdx.x;
    const int* dst = (g == 0) ? d0 : (g == 1) ? d1 : d2;
    const int E = (g == 0) ? e0 : (g == 1) ? e1 : e2;
    __shared__ unsigned hist[NBK];
    hist[t] = 0;
    __syncthreads();
    const int chunk = (E + BINB - 1) / BINB;
    const int i0 = blk * chunk, i1 = min(E, i0 + chunk);
    for (int i = i0 + t; i < i1; i += 256) atomicAdd(&hist[((unsigned)dst[i]) >> 8], 1u);
    __syncthreads();
    cnts[((size_t)(g * NBK + t)) * BINB + blk] = hist[t];
}

// (2a) block sums for global exclusive scan over 3*NBK*BINB values (768 blocks x 512)
__global__ __launch_bounds__(256) void k_sa(const unsigned* __restrict__ cnts,
                                            unsigned* __restrict__ bs) {
    const int blk = blockIdx.x, t = threadIdx.x;
    unsigned s = cnts[(size_t)blk * 512 + t] + cnts[(size_t)blk * 512 + 256 + t];
    __shared__ unsigned red[256];
    red[t] = s;
    __syncthreads();
    for (int o = 128; o; o >>= 1) {
        if (t < o) red[t] += red[t + o];
        __syncthreads();
    }
    if (t == 0) bs[blk] = red[0];
}

// (2b) exclusive scan of the 768 block sums (one block, 1024 threads)
__global__ void k_sb(unsigned* __restrict__ bs, int n) {
    const int t = threadIdx.x;
    __shared__ unsigned ps[1024];
    unsigned v = (t < n) ? bs[t] : 0u;
    ps[t] = v;
    __syncthreads();
    for (int o = 1; o < 1024; o <<= 1) {
        const unsigned a = (t >= o) ? ps[t - o] : 0u;
        __syncthreads();
        ps[t] += a;
        __syncthreads();
    }
    if (t < n) bs[t] = ps[t] - v;
}

// (2c) in-place exclusive positions (thread t handles elements 2t, 2t+1 of its 512-chunk)
__global__ __launch_bounds__(256) void k_sc(unsigned* __restrict__ cnts,
                                            const unsigned* __restrict__ bs) {
    const int blk = blockIdx.x, t = threadIdx.x;
    const size_t base = (size_t)blk * 512;
    const unsigned e0v = cnts[base + 2 * t];
    const unsigned e1v = cnts[base + 2 * t + 1];
    const unsigned pair = e0v + e1v;
    __shared__ unsigned ps[256];
    ps[t] = pair;
    __syncthreads();
    for (int o = 1; o < 256; o <<= 1) {
        const unsigned a = (t >= o) ? ps[t - o] : 0u;
        __syncthreads();
        ps[t] += a;
        __syncthreads();
    }
    const unsigned ex = ps[t] - pair + bs[blk];
    cnts[base + 2 * t]     = ex;
    cnts[base + 2 * t + 1] = ex + e0v;
}

// (3) place (src,dst) records into per-(block,bucket) deterministic segments of ebuf
__global__ __launch_bounds__(256) void k_binplace(
    const int* __restrict__ s0, const int* __restrict__ d0,
    const int* __restrict__ s1, const int* __restrict__ d1,
    const int* __restrict__ s2, const int* __restrict__ d2,
    int e0, int e1, int e2, const unsigned* __restrict__ pos, int2* __restrict__ ebuf) {
    const int g = blockIdx.y, blk = blockIdx.x, t = threadIdx.x;
    const int* src = (g == 0) ? s0 : (g == 1) ? s1 : s2;
    const int* dst = (g == 0) ? d0 : (g == 1) ? d1 : d2;
    const int E = (g == 0) ? e0 : (g == 1) ? e1 : e2;
    __shared__ unsigned cur[NBK];
    cur[t] = pos[((size_t)(g * NBK + t)) * BINB + blk];
    __syncthreads();
    const int chunk = (E + BINB - 1) / BINB;
    const int i0 = blk * chunk, i1 = min(E, i0 + chunk);
    for (int i = i0 + t; i < i1; i += 256) {
        const int dv = dst[i];
        const unsigned p = atomicAdd(&cur[((unsigned)dv) >> 8], 1u);
        ebuf[p] = make_int2(src[i], dv);
    }
}

// (4) per-bucket CSR finalize: deg/scan/off/cend/rinv + nbr placement (block-private region)
__global__ __launch_bounds__(256) void k_build(
    const int2* __restrict__ ebuf, const unsigned* __restrict__ pos,
    int etot, int e0, int e1,
    int* __restrict__ off, int* __restrict__ cend, float* __restrict__ rinv,
    int* __restrict__ n0, int* __restrict__ n1, int* __restrict__ n2, int N) {
    const int g = blockIdx.y, b = blockIdx.x, t = threadIdx.x;
    const int v0 = b << 8;
    const int gbase = (g == 0) ? 0 : ((g == 1) ? e0 : e0 + e1);
    int* nbr = (g == 0) ? n0 : ((g == 1) ? n1 : n2);
    const int cell = g * NBK + b;
    const unsigned seg0 = pos[(size_t)cell * BINB];
    const unsigned seg1 = (cell + 1 < 3 * NBK) ? pos[(size_t)(cell + 1) * BINB] : (unsigned)etot;

    __shared__ unsigned deg[NBK];
    __shared__ unsigned ps[NBK];
    __shared__ unsigned cur[NBK];
    deg[t] = 0;
    __syncthreads();
    for (unsigned i = seg0 + t; i < seg1; i += 256) atomicAdd(&deg[ebuf[i].y - v0], 1u);
    __syncthreads();
    const unsigned dv = deg[t];
    ps[t] = dv;
    __syncthreads();
    for (int o = 1; o < 256; o <<= 1) {
        const unsigned a = (t >= o) ? ps[t - o] : 0u;
        __syncthreads();
        ps[t] += a;
        __syncthreads();
    }
    const unsigned ex = ps[t] - dv;     // exclusive within bucket
    const int nbase = (int)seg0 - gbase;
    const int node = v0 + t;
    if (node < N) {
        off[(size_t)g * N + node]  = nbase + (int)ex;
        cend[(size_t)g * N + node] = nbase + (int)(ex + dv);
        rinv[(size_t)g * N + node] = 1.0f / ((float)dv + 1.0f);
    }
    cur[t] = ex;
    __syncthreads();
    for (unsigned i = seg0 + t; i < seg1; i += 256) {
        const int2 e = ebuf[i];
        const unsigned p = atomicAdd(&cur[e.y - v0], 1u);
        nbr[nbase + (int)p] = e.x;
    }
}

// ---------------- gather (bf16 x rows, 3 graphs via blockIdx.y), BN1 fused ----------------
__global__ __launch_bounds__(256) void k_gather3(
    const unsigned short* __restrict__ XB,
    const int* __restrict__ nbr0, const int* __restrict__ nbr1, const int* __restrict__ nbr2,
    const int* __restrict__ off, const int* __restrict__ cend,
    const float* __restrict__ rinv, const float* __restrict__ s1,
    const float* __restrict__ sh1, float* __restrict__ AGG3, int N) {
    const int g = blockIdx.y;
    const int* nbr = (g == 0) ? nbr0 : (g == 1) ? nbr1 : nbr2;
    const int gb = g * N;
    const int wave = threadIdx.x >> 6;
    const int lane = threadIdx.x & 63;
    const int v = blockIdx.x * 4 + wave;
    if (v >= N) return;
    const int i0 = off[gb + v], i1 = cend[gb + v];
    const int l2 = lane * 2;
    unsigned sv = ((const unsigned*)(XB + (size_t)v * FDIM))[lane];
    float2 acc;
    acc.x = blo(sv);
    acc.y = bhi(sv);
    int i = i0;
    for (; i + 8 <= i1; i += 8) {
        const int u0 = nbr[i],     u1 = nbr[i + 1], u2 = nbr[i + 2], u3 = nbr[i + 3];
        const int u4 = nbr[i + 4], u5 = nbr[i + 5], u6 = nbr[i + 6], u7 = nbr[i + 7];
        const unsigned a0 = ((const unsigned*)(XB + (size_t)u0 * FDIM))[lane];
        const unsigned a1 = ((const unsigned*)(XB + (size_t)u1 * FDIM))[lane];
        const unsigned a2 = ((const unsigned*)(XB + (size_t)u2 * FDIM))[lane];
        const unsigned a3 = ((const unsigned*)(XB + (size_t)u3 * FDIM))[lane];
        const unsigned a4 = ((const unsigned*)(XB + (size_t)u4 * FDIM))[lane];
        const unsigned a5 = ((const unsigned*)(XB + (size_t)u5 * FDIM))[lane];
        const unsigned a6 = ((const unsigned*)(XB + (size_t)u6 * FDIM))[lane];
        const unsigned a7 = ((const unsigned*)(XB + (size_t)u7 * FDIM))[lane];
        acc.x += ((blo(a0) + blo(a1)) + (blo(a2) + blo(a3))) + ((blo(a4) + blo(a5)) + (blo(a6) + blo(a7)));
        acc.y += ((bhi(a0) + bhi(a1)) + (bhi(a2) + bhi(a3))) + ((bhi(a4) + bhi(a5)) + (bhi(a6) + bhi(a7)));
    }
    for (; i < i1; ++i) {
        const unsigned a = ((const unsigned*)(XB + (size_t)nbr[i] * FDIM))[lane];
        acc.x += blo(a);
        acc.y += bhi(a);
    }
    const float r = rinv[gb + v];
    const float2 sc = *(const float2*)&s1[l2];
    const float2 sh = *(const float2*)&sh1[l2];
    float2 o;
    o.x = fmaf(acc.x * r, sc.x, sh.x);
    o.y = fmaf(acc.y * r, sc.y, sh.y);
    *(float2*)&AGG3[((size_t)gb + v) * FDIM + l2] = o;
}

// ---------------- GEMM1: H = relu( [AGG3_0|AGG3_1|AGG3_2] @ [W1;W2;W3] + sum b ), K=384 ----------------
__global__ __launch_bounds__(256) void k_gemm1(
    const float* __restrict__ AGG3,
    const float* __restrict__ W1, const float* __restrict__ W2, const float* __restrict__ W3,
    const float* __restrict__ b1, const float* __restrict__ b2, const float* __restrict__ b3,
    float* __restrict__ H, int N) {
    __shared__ float At[16][64];
    __shared__ float Bt[16][128];
    const int t = threadIdx.x;
    const int row0 = blockIdx.x * 64;
    const int c0 = (t & 31) * 4;     // 0..124
    const int r0 = (t >> 5) * 8;     // 0..56
    float acc[8][4];
    #pragma unroll
    for (int r = 0; r < 8; ++r)
        #pragma unroll
        for (int c = 0; c < 4; ++c) acc[r][c] = 0.f;

    for (int kb = 0; kb < 24; ++kb) {      // K = 384, tiles of 16
        const int g = kb >> 3;
        const int kloc0 = (kb & 7) * 16;
        const float* Ag = AGG3 + (size_t)g * N * FDIM;
        const float* Wg = (g == 0) ? W1 : (g == 1) ? W2 : W3;
        {
            const int kk = t & 15;
            const int rb = t >> 4;          // 0..15
            #pragma unroll
            for (int it = 0; it < 4; ++it) {
                const int r = rb + it * 16;
                const int row = row0 + r;
                At[kk][r] = (row < N) ? Ag[(size_t)row * FDIM + kloc0 + kk] : 0.f;
            }
        }
        {
            const int n = t & 127;
            const int kkb = t >> 7;         // 0..1
            #pragma unroll
            for (int it = 0; it < 8; ++it) {
                const int kk = kkb + it * 2;
                Bt[kk][n] = Wg[(size_t)(kloc0 + kk) * 128 + n];
            }
        }
        __syncthreads();
        #pragma unroll
        for (int kk = 0; kk < 16; ++kk) {
            const float4 b  = *(const float4*)&Bt[kk][c0];
            const float4 a0 = *(const float4*)&At[kk][r0];
            const float4 a1 = *(const float4*)&At[kk][r0 + 4];
            const float a[8] = {a0.x, a0.y, a0.z, a0.w, a1.x, a1.y, a1.z, a1.w};
            #pragma unroll
            for (int r = 0; r < 8; ++r) {
                acc[r][0] = fmaf(a[r], b.x, acc[r][0]);
                acc[r][1] = fmaf(a[r], b.y, acc[r][1]);
                acc[r][2] = fmaf(a[r], b.z, acc[r][2]);
                acc[r][3] = fmaf(a[r], b.w, acc[r][3]);
            }
        }
        __syncthreads();
    }
    float4 base;
    base.x = b1[c0 + 0] + b2[c0 + 0] + b3[c0 + 0];
    base.y = b1[c0 + 1] + b2[c0 + 1] + b3[c0 + 1];
    base.z = b1[c0 + 2] + b2[c0 + 2] + b3[c0 + 2];
    base.w = b1[c0 + 3] + b2[c0 + 3] + b3[c0 + 3];
    #pragma unroll
    for (int r = 0; r < 8; ++r) {
        const int row = row0 + r0 + r;
        if (row < N) {
            float4 o;
            o.x = fmaxf(acc[r][0] + base.x, 0.f);
            o.y = fmaxf(acc[r][1] + base.y, 0.f);
            o.z = fmaxf(acc[r][2] + base.z, 0.f);
            o.w = fmaxf(acc[r][3] + base.w, 0.f);
            *(float4*)&H[(size_t)row * FDIM + c0] = o;
        }
    }
}

// ---------------- c2[g][n] = sum_k sh2[k] * Wg[k][n] ----------------
__global__ void k_c2(const float* __restrict__ sh2,
                     const float* __restrict__ W1, const float* __restrict__ W2,
                     const float* __restrict__ W3, float* __restrict__ c2) {
    const int t = threadIdx.x;   // 192
    const int g = t >> 6, n = t & 63;
    const float* W = (g == 0) ? W1 : (g == 1) ? W2 : W3;
    float s = 0.f;
    for (int k = 0; k < 128; ++k) s = fmaf(sh2[k], W[(size_t)k * ODIM + n], s);
    c2[g * ODIM + n] = s;
}

// ---------------- GEMM2 (BN2 scale fused): U_g = bf16( (H*s2) @ W_g2 + c2_g ) ----------------
__global__ __launch_bounds__(256) void k_gemm2(
    const float* __restrict__ H, const float* __restrict__ s2,
    const float* __restrict__ W1, const float* __restrict__ W2, const float* __restrict__ W3,
    const float* __restrict__ c2, unsigned short* __restrict__ Ub, int N) {
    __shared__ float At[16][64];
    __shared__ float Bt[16][64];
    const int t = threadIdx.x;
    const int g = blockIdx.y;
    const int row0 = blockIdx.x * 64;
    const int c0 = (t & 15) * 4;     // 0..60
    const int r0 = (t >> 4) * 4;     // 0..60
    const float* Wg = (g == 0) ? W1 : (g == 1) ? W2 : W3;
    float acc[4][4];
    #pragma unroll
    for (int r = 0; r < 4; ++r)
        #pragma unroll
        for (int c = 0; c < 4; ++c) acc[r][c] = 0.f;

    for (int kb = 0; kb < 8; ++kb) {       // K = 128
        const int k0 = kb * 16;
        {
            const int kk = t & 15;
            const int rb = t >> 4;          // 0..15
            const float sv = s2[k0 + kk];
            #pragma unroll
            for (int it = 0; it < 4; ++it) {
                const int r = rb + it * 16;
                const int row = row0 + r;
                At[kk][r] = (row < N) ? H[(size_t)row * FDIM + k0 + kk] * sv : 0.f;
            }
        }
        {
            const int n = t & 63;
            const int kkb = t >> 6;         // 0..3
            #pragma unroll
            for (int it = 0; it < 4; ++it) {
                const int kk = kkb + it * 4;
                Bt[kk][n] = Wg[(size_t)(k0 + kk) * ODIM + n];
            }
        }
        __syncthreads();
        #pragma unroll
        for (int kk = 0; kk < 16; ++kk) {
            const float4 b = *(const float4*)&Bt[kk][c0];
            const float4 a = *(const float4*)&At[kk][r0];
            const float av[4] = {a.x, a.y, a.z, a.w};
            #pragma unroll
            for (int r = 0; r < 4; ++r) {
                acc[r][0] = fmaf(av[r], b.x, acc[r][0]);
                acc[r][1] = fmaf(av[r], b.y, acc[r][1]);
                acc[r][2] = fmaf(av[r], b.z, acc[r][2]);
                acc[r][3] = fmaf(av[r], b.w, acc[r][3]);
            }
        }
        __syncthreads();
    }
    const float* cg = c2 + (size_t)g * ODIM;
    unsigned short* Ug = Ub + (size_t)g * N * ODIM;
    #pragma unroll
    for (int r = 0; r < 4; ++r) {
        const int row = row0 + r0 + r;
        if (row < N) {
            uint2 w;
            w.x = (unsigned)f2bf(acc[r][0] + cg[c0 + 0]) | ((unsigned)f2bf(acc[r][1] + cg[c0 + 1]) << 16);
            w.y = (unsigned)f2bf(acc[r][2] + cg[c0 + 2]) | ((unsigned)f2bf(acc[r][3] + cg[c0 + 3]) << 16);
            *(uint2*)&Ug[(size_t)row * ODIM + c0] = w;
        }
    }
}

// ---------------- layer-2 gather + combine (bf16 U rows) ----------------
__global__ __launch_bounds__(256) void k_gc64(
    const unsigned short* __restrict__ Ub,
    const int* __restrict__ nbr0, const int* __restrict__ nbr1, const int* __restrict__ nbr2,
    const int* __restrict__ off, const int* __restrict__ cend,
    const float* __restrict__ rinv,
    const float* __restrict__ b1, const float* __restrict__ b2, const float* __restrict__ b3,
    float* __restrict__ Z, int N) {
    const int wave = threadIdx.x >> 6;
    const int lane = threadIdx.x & 63;
    const int v = blockIdx.x * 4 + wave;
    if (v >= N) return;
    const size_t gs = (size_t)N * ODIM;
    float z = b1[lane] + b2[lane] + b3[lane];
    #pragma unroll
    for (int g = 0; g < 3; ++g) {
        const unsigned short* Ug = Ub + (size_t)g * gs;
        const int* nb = (g == 0) ? nbr0 : (g == 1) ? nbr1 : nbr2;
        const int i0 = off[g * N + v], i1 = cend[g * N + v];
        float s = bf2f(Ug[(size_t)v * ODIM + lane]);
        int i = i0;
        for (; i + 8 <= i1; i += 8) {
            const int u0 = nb[i],     u1 = nb[i + 1], u2 = nb[i + 2], u3 = nb[i + 3];
            const int u4 = nb[i + 4], u5 = nb[i + 5], u6 = nb[i + 6], u7 = nb[i + 7];
            const float a0 = bf2f(Ug[(size_t)u0 * ODIM + lane]);
            const float a1 = bf2f(Ug[(size_t)u1 * ODIM + lane]);
            const float a2 = bf2f(Ug[(size_t)u2 * ODIM + lane]);
            const float a3 = bf2f(Ug[(size_t)u3 * ODIM + lane]);
            const float a4 = bf2f(Ug[(size_t)u4 * ODIM + lane]);
            const float a5 = bf2f(Ug[(size_t)u5 * ODIM + lane]);
            const float a6 = bf2f(Ug[(size_t)u6 * ODIM + lane]);
            const float a7 = bf2f(Ug[(size_t)u7 * ODIM + lane]);
            s += ((a0 + a1) + (a2 + a3)) + ((a4 + a5) + (a6 + a7));
        }
        for (; i < i1; ++i) s += bf2f(Ug[(size_t)nb[i] * ODIM + lane]);
        z += s * rinv[g * N + v];
    }
    Z[(size_t)v * ODIM + lane] = z;
}

// ---------------- final: BN3 + sigmoid + row min-max + row L2, in place ----------------
__global__ __launch_bounds__(256) void k_final(float* __restrict__ Z,
                                               const float* __restrict__ scale,
                                               const float* __restrict__ shift, int N) {
    const int wave = threadIdx.x >> 6;
    const int lane = threadIdx.x & 63;
    const int row = blockIdx.x * 4 + wave;
    if (row >= N) return;
    float v = fmaf(Z[(size_t)row * ODIM + lane], scale[lane], shift[lane]);
    float s = 1.0f / (1.0f + expf(-v));
    float mn = s, mx = s;
    #pragma unroll
    for (int off = 32; off; off >>= 1) {
        mn = fminf(mn, __shfl_xor(mn, off, 64));
        mx = fmaxf(mx, __shfl_xor(mx, off, 64));
    }
    const float sc = (s - mn) / (mx - mn);
    float sq = sc * sc;
    #pragma unroll
    for (int off = 32; off; off >>= 1) sq += __shfl_xor(sq, off, 64);
    const float norm = fmaxf(sqrtf(sq), 1e-12f);
    Z[(size_t)row * ODIM + lane] = sc / norm;
}

extern "C" void kernel_launch(void* const* d_in, const int* in_sizes, int n_in,
                              void* d_out, int out_size, void* d_ws, size_t ws_size,
                              hipStream_t stream) {
    const float* x = (const float*)d_in[0];
    const int* src[3] = {(const int*)d_in[1], (const int*)d_in[3], (const int*)d_in[5]};
    const int* dst[3] = {(const int*)d_in[2], (const int*)d_in[4], (const int*)d_in[6]};
    const int E[3] = {in_sizes[1], in_sizes[3], in_sizes[5]};
    const int Etot = E[0] + E[1] + E[2];
    const float* W11 = (const float*)d_in[7];  const float* b11 = (const float*)d_in[8];
    const float* W21 = (const float*)d_in[9];  const float* b21 = (const float*)d_in[10];
    const float* W31 = (const float*)d_in[11]; const float* b31 = (const float*)d_in[12];
    const float* W12 = (const float*)d_in[13]; const float* b12 = (const float*)d_in[14];
    const float* W22 = (const float*)d_in[15]; const float* b22 = (const float*)d_in[16];
    const float* W32 = (const float*)d_in[17]; const float* b32 = (const float*)d_in[18];
    const float* g1  = (const float*)d_in[19]; const float* be1 = (const float*)d_in[20];
    const float* g2  = (const float*)d_in[21]; const float* be2 = (const float*)d_in[22];
    const float* g3  = (const float*)d_in[23]; const float* be3 = (const float*)d_in[24];
    const int N = in_sizes[0] / FDIM;
    float* Z = (float*)d_out;

    // ---- workspace layout ----
    // floats: H (N*128) | AGG3 (3*N*128) | rinv 3N | partial 65536 | scales | c2
    // xb (bf16) aliases H; Ub (bf16) aliases AGG3 start;
    // ebuf (int2, Etot) + cnts (3*NBK*BINB u32) + bs (768) alias AGG3 (dead until gather3)
    float* ws   = (float*)d_ws;
    float* H    = ws;                          // N*128
    unsigned short* xb = (unsigned short*)H;
    float* AGG3 = H + (size_t)N * FDIM;        // 3*N*128
    unsigned short* Ub = (unsigned short*)AGG3;
    int2* ebuf = (int2*)AGG3;                                  // Etot int2 (16 MB-ish)
    unsigned* cnts = (unsigned*)(ebuf + (size_t)Etot);         // 3*NBK*BINB
    unsigned* bs   = cnts + (size_t)3 * NBK * BINB;            // 768
    float* rinv = AGG3 + (size_t)3 * N * FDIM; // 3N
    float* partial = rinv + (size_t)3 * N;     // 65536
    float* s1  = partial + 65536;  float* sh1 = s1 + 128;
    float* s2  = sh1 + 128;        float* sh2 = s2 + 128;
    float* s3  = sh2 + 128;        float* sh3 = s3 + 64;
    float* c2  = sh3 + 64;                     // 3*64
    // int region
    int* off  = (int*)(c2 + 3 * ODIM);                    // 3N
    int* cend = off + (size_t)3 * N;                      // 3N
    int* nbr  = cend + (size_t)3 * N;                     // Etot
    int* nbrg[3];
    nbrg[0] = nbr;
    nbrg[1] = nbrg[0] + E[0];
    nbrg[2] = nbrg[1] + E[1];

    // ---- CSR build via bucket binning (single-writer nbr lines) ----
    const int nbuckets = (N + 255) >> 8;
    k_bincount<<<dim3(BINB, 3), 256, 0, stream>>>(dst[0], dst[1], dst[2],
                                                  E[0], E[1], E[2], cnts);
    k_sa<<<3 * NBK * BINB / 512, 256, 0, stream>>>(cnts, bs);
    k_sb<<<1, 1024, 0, stream>>>(bs, 3 * NBK * BINB / 512);
    k_sc<<<3 * NBK * BINB / 512, 256, 0, stream>>>(cnts, bs);
    k_binplace<<<dim3(BINB, 3), 256, 0, stream>>>(src[0], dst[0], src[1], dst[1],
                                                  src[2], dst[2], E[0], E[1], E[2],
                                                  cnts, ebuf);
    k_build<<<dim3(nbuckets, 3), 256, 0, stream>>>(ebuf, cnts, Etot, E[0], E[1],
                                                   off, cend, rinv,
                                                   nbrg[0], nbrg[1], nbrg[2], N);

    // ---- BN1 stats + bf16 conversion of x ----
    k_colstats<128><<<256, 128, 0, stream>>>(x, N, partial);
    k_colstats_fin<128><<<1, 128, 0, stream>>>(partial, 256, N, g1, be1, s1, sh1);
    k_cvt<<<1024, 256, 0, stream>>>(x, xb, (size_t)N * FDIM / 8);

    // ---- layer 1: 3-graph bf16 gather -> single K=384 GEMM ----
    const int gblocks = (N + 3) / 4;
    k_gather3<<<dim3(gblocks, 3), 256, 0, stream>>>(xb, nbrg[0], nbrg[1], nbrg[2],
                                                    off, cend, rinv, s1, sh1, AGG3, N);
    k_gemm1<<<(N + 63) / 64, 256, 0, stream>>>(AGG3, W11, W21, W31, b11, b21, b31, H, N);

    // ---- BN2 stats (scale fused into GEMM2 A-load, shift folded via c2) ----
    k_colstats<128><<<256, 128, 0, stream>>>(H, N, partial);
    k_colstats_fin<128><<<1, 128, 0, stream>>>(partial, 256, N, g2, be2, s2, sh2);
    k_c2<<<1, 192, 0, stream>>>(sh2, W12, W22, W32, c2);

    // ---- layer 2: GEMM first (bf16 U over dead AGG3), then bf16 gather+combine ----
    dim3 grid2((N + 63) / 64, 3);
    k_gemm2<<<grid2, 256, 0, stream>>>(H, s2, W12, W22, W32, c2, Ub, N);
    k_gc64<<<gblocks, 256, 0, stream>>>(Ub, nbrg[0], nbrg[1], nbrg[2], off, cend, rinv,
                                        b12, b22, b32, Z, N);

    // ---- BN3 + epilogue ----
    k_colstats<64><<<256, 64, 0, stream>>>(Z, N, partial);
    k_colstats_fin<64><<<1, 64, 0, stream>>>(partial, 256, N, g3, be3, s3, sh3);
    k_final<<<(N + 3) / 4, 256, 0, stream>>>(Z, s3, sh3, N);
}

// Round 10
// 758.943 us; speedup vs baseline: 1.5956x; 1.0041x over previous
//
#include <hip/hip_runtime.h>
#include <math.h>

constexpr int FDIM = 128;   // IN == HID
constexpr int ODIM = 64;    // NC
constexpr int BINB = 512;   // binning blocks per graph
constexpr int NBK  = 256;   // max buckets (256 nodes each -> N <= 65536)

// bf16 helpers (RNE pack, bit-shift unpack)
__device__ inline unsigned short f2bf(float f) {
    unsigned u = __float_as_uint(f);
    u = (u + 0x7fffu + ((u >> 16) & 1u)) >> 16;
    return (unsigned short)u;
}
__device__ inline float bf2f(unsigned short s) { return __uint_as_float(((unsigned)s) << 16); }
__device__ inline float blo(unsigned v) { return __uint_as_float(v << 16); }
__device__ inline float bhi(unsigned v) { return __uint_as_float(v & 0xffff0000u); }

// ---------------- column stats (deterministic two-stage) ----------------
template<int C>
__global__ void k_colstats(const float* __restrict__ X, int N, float* __restrict__ partial) {
    const int c = threadIdx.x;          // blockDim.x == C
    const int nb = gridDim.x;
    const int rows_per = (N + nb - 1) / nb;
    const int r0 = blockIdx.x * rows_per;
    const int r1 = min(N, r0 + rows_per);
    float s = 0.f, ss = 0.f;
    for (int r = r0; r < r1; ++r) {
        float v = X[(size_t)r * C + c];
        s += v;
        ss += v * v;
    }
    partial[(size_t)blockIdx.x * (2 * C) + c]     = s;
    partial[(size_t)blockIdx.x * (2 * C) + C + c] = ss;
}

// BN1 variant: also emits bf16 copy of X (each element read exactly once)
__global__ void k_colstats_cvt(const float* __restrict__ X, int N,
                               float* __restrict__ partial, unsigned short* __restrict__ XB) {
    const int c = threadIdx.x;          // blockDim.x == 128
    const int nb = gridDim.x;
    const int rows_per = (N + nb - 1) / nb;
    const int r0 = blockIdx.x * rows_per;
    const int r1 = min(N, r0 + rows_per);
    float s = 0.f, ss = 0.f;
    for (int r = r0; r < r1; ++r) {
        float v = X[(size_t)r * 128 + c];
        s += v;
        ss += v * v;
        XB[(size_t)r * 128 + c] = f2bf(v);
    }
    partial[(size_t)blockIdx.x * 256 + c]       = s;
    partial[(size_t)blockIdx.x * 256 + 128 + c] = ss;
}

template<int C>
__global__ void k_colstats_fin(const float* __restrict__ partial, int nb, int N,
                               const float* __restrict__ gamma, const float* __restrict__ beta,
                               float* __restrict__ scale, float* __restrict__ shift) {
    const int c = threadIdx.x;          // blockDim.x == C
    float s = 0.f, ss = 0.f;
    for (int b = 0; b < nb; ++b) {
        s  += partial[(size_t)b * (2 * C) + c];
        ss += partial[(size_t)b * (2 * C) + C + c];
    }
    const float mu  = s / (float)N;
    const float var = ss / (float)N - mu * mu;
    const float sc  = gamma[c] * rsqrtf(var + 1e-5f);
    scale[c] = sc;
    shift[c] = beta[c] - mu * sc;
}

// ================= CSR build via bucket binning (single-writer nbr lines) =================
__global__ __launch_bounds__(256) void k_bincount(
    const int* __restrict__ d0, const int* __restrict__ d1, const int* __restrict__ d2,
    int e0, int e1, int e2, unsigned* __restrict__ cnts) {
    const int g = blockIdx.y, blk = blockIdx.x, t = threadIdx.x;
    const int* dst = (g == 0) ? d0 : (g == 1) ? d1 : d2;
    const int E = (g == 0) ? e0 : (g == 1) ? e1 : e2;
    __shared__ unsigned hist[NBK];
    hist[t] = 0;
    __syncthreads();
    const int chunk = (E + BINB - 1) / BINB;
    const int i0 = blk * chunk, i1 = min(E, i0 + chunk);
    for (int i = i0 + t; i < i1; i += 256) atomicAdd(&hist[((unsigned)dst[i]) >> 8], 1u);
    __syncthreads();
    cnts[((size_t)(g * NBK + t)) * BINB + blk] = hist[t];
}

__global__ __launch_bounds__(256) void k_sa(const unsigned* __restrict__ cnts,
                                            unsigned* __restrict__ bs) {
    const int blk = blockIdx.x, t = threadIdx.x;
    unsigned s = cnts[(size_t)blk * 512 + t] + cnts[(size_t)blk * 512 + 256 + t];
    __shared__ unsigned red[256];
    red[t] = s;
    __syncthreads();
    for (int o = 128; o; o >>= 1) {
        if (t < o) red[t] += red[t + o];
        __syncthreads();
    }
    if (t == 0) bs[blk] = red[0];
}

__global__ void k_sb(unsigned* __restrict__ bs, int n) {
    const int t = threadIdx.x;
    __shared__ unsigned ps[1024];
    unsigned v = (t < n) ? bs[t] : 0u;
    ps[t] = v;
    __syncthreads();
    for (int o = 1; o < 1024; o <<= 1) {
        const unsigned a = (t >= o) ? ps[t - o] : 0u;
        __syncthreads();
        ps[t] += a;
        __syncthreads();
    }
    if (t < n) bs[t] = ps[t] - v;
}

__global__ __launch_bounds__(256) void k_sc(unsigned* __restrict__ cnts,
                                            const unsigned* __restrict__ bs) {
    const int blk = blockIdx.x, t = threadIdx.x;
    const size_t base = (size_t)blk * 512;
    const unsigned e0v = cnts[base + 2 * t];
    const unsigned e1v = cnts[base + 2 * t + 1];
    const unsigned pair = e0v + e1v;
    __shared__ unsigned ps[256];
    ps[t] = pair;
    __syncthreads();
    for (int o = 1; o < 256; o <<= 1) {
        const unsigned a = (t >= o) ? ps[t - o] : 0u;
        __syncthreads();
        ps[t] += a;
        __syncthreads();
    }
    const unsigned ex = ps[t] - pair + bs[blk];
    cnts[base + 2 * t]     = ex;
    cnts[base + 2 * t + 1] = ex + e0v;
}

__global__ __launch_bounds__(256) void k_binplace(
    const int* __restrict__ s0, const int* __restrict__ d0,
    const int* __restrict__ s1, const int* __restrict__ d1,
    const int* __restrict__ s2, const int* __restrict__ d2,
    int e0, int e1, int e2, const unsigned* __restrict__ pos, int2* __restrict__ ebuf) {
    const int g = blockIdx.y, blk = blockIdx.x, t = threadIdx.x;
    const int* src = (g == 0) ? s0 : (g == 1) ? s1 : s2;
    const int* dst = (g == 0) ? d0 : (g == 1) ? d1 : d2;
    const int E = (g == 0) ? e0 : (g == 1) ? e1 : e2;
    __shared__ unsigned cur[NBK];
    cur[t] = pos[((size_t)(g * NBK + t)) * BINB + blk];
    __syncthreads();
    const int chunk = (E + BINB - 1) / BINB;
    const int i0 = blk * chunk, i1 = min(E, i0 + chunk);
    for (int i = i0 + t; i < i1; i += 256) {
        const int dv = dst[i];
        const unsigned p = atomicAdd(&cur[((unsigned)dv) >> 8], 1u);
        ebuf[p] = make_int2(src[i], dv);
    }
}

__global__ __launch_bounds__(256) void k_build(
    const int2* __restrict__ ebuf, const unsigned* __restrict__ pos,
    int etot, int e0, int e1,
    int* __restrict__ off, int* __restrict__ cend, float* __restrict__ rinv,
    int* __restrict__ n0, int* __restrict__ n1, int* __restrict__ n2, int N) {
    const int g = blockIdx.y, b = blockIdx.x, t = threadIdx.x;
    const int v0 = b << 8;
    const int gbase = (g == 0) ? 0 : ((g == 1) ? e0 : e0 + e1);
    int* nbr = (g == 0) ? n0 : ((g == 1) ? n1 : n2);
    const int cell = g * NBK + b;
    const unsigned seg0 = pos[(size_t)cell * BINB];
    const unsigned seg1 = (cell + 1 < 3 * NBK) ? pos[(size_t)(cell + 1) * BINB] : (unsigned)etot;

    __shared__ unsigned deg[NBK];
    __shared__ unsigned ps[NBK];
    __shared__ unsigned cur[NBK];
    deg[t] = 0;
    __syncthreads();
    for (unsigned i = seg0 + t; i < seg1; i += 256) atomicAdd(&deg[ebuf[i].y - v0], 1u);
    __syncthreads();
    const unsigned dv = deg[t];
    ps[t] = dv;
    __syncthreads();
    for (int o = 1; o < 256; o <<= 1) {
        const unsigned a = (t >= o) ? ps[t - o] : 0u;
        __syncthreads();
        ps[t] += a;
        __syncthreads();
    }
    const unsigned ex = ps[t] - dv;     // exclusive within bucket
    const int nbase = (int)seg0 - gbase;
    const int node = v0 + t;
    if (node < N) {
        off[(size_t)g * N + node]  = nbase + (int)ex;
        cend[(size_t)g * N + node] = nbase + (int)(ex + dv);
        rinv[(size_t)g * N + node] = 1.0f / ((float)dv + 1.0f);
    }
    cur[t] = ex;
    __syncthreads();
    for (unsigned i = seg0 + t; i < seg1; i += 256) {
        const int2 e = ebuf[i];
        const unsigned p = atomicAdd(&cur[e.y - v0], 1u);
        nbr[nbase + (int)p] = e.x;
    }
}

// ---------------- gather (bf16 x rows, 3 graphs via blockIdx.y), BN1 fused, bf16 out ----------------
__global__ __launch_bounds__(256) void k_gather3(
    const unsigned short* __restrict__ XB,
    const int* __restrict__ nbr0, const int* __restrict__ nbr1, const int* __restrict__ nbr2,
    const int* __restrict__ off, const int* __restrict__ cend,
    const float* __restrict__ rinv, const float* __restrict__ s1,
    const float* __restrict__ sh1, unsigned short* __restrict__ AGG3b, int N) {
    const int g = blockIdx.y;
    const int* nbr = (g == 0) ? nbr0 : (g == 1) ? nbr1 : nbr2;
    const int gb = g * N;
    const int wave = threadIdx.x >> 6;
    const int lane = threadIdx.x & 63;
    const int v = blockIdx.x * 4 + wave;
    if (v >= N) return;
    const int i0 = off[gb + v], i1 = cend[gb + v];
    const int l2 = lane * 2;
    unsigned sv = ((const unsigned*)(XB + (size_t)v * FDIM))[lane];
    float2 acc;
    acc.x = blo(sv);
    acc.y = bhi(sv);
    int i = i0;
    for (; i + 8 <= i1; i += 8) {
        const int u0 = nbr[i],     u1 = nbr[i + 1], u2 = nbr[i + 2], u3 = nbr[i + 3];
        const int u4 = nbr[i + 4], u5 = nbr[i + 5], u6 = nbr[i + 6], u7 = nbr[i + 7];
        const unsigned a0 = ((const unsigned*)(XB + (size_t)u0 * FDIM))[lane];
        const unsigned a1 = ((const unsigned*)(XB + (size_t)u1 * FDIM))[lane];
        const unsigned a2 = ((const unsigned*)(XB + (size_t)u2 * FDIM))[lane];
        const unsigned a3 = ((const unsigned*)(XB + (size_t)u3 * FDIM))[lane];
        const unsigned a4 = ((const unsigned*)(XB + (size_t)u4 * FDIM))[lane];
        const unsigned a5 = ((const unsigned*)(XB + (size_t)u5 * FDIM))[lane];
        const unsigned a6 = ((const unsigned*)(XB + (size_t)u6 * FDIM))[lane];
        const unsigned a7 = ((const unsigned*)(XB + (size_t)u7 * FDIM))[lane];
        acc.x += ((blo(a0) + blo(a1)) + (blo(a2) + blo(a3))) + ((blo(a4) + blo(a5)) + (blo(a6) + blo(a7)));
        acc.y += ((bhi(a0) + bhi(a1)) + (bhi(a2) + bhi(a3))) + ((bhi(a4) + bhi(a5)) + (bhi(a6) + bhi(a7)));
    }
    for (; i < i1; ++i) {
        const unsigned a = ((const unsigned*)(XB + (size_t)nbr[i] * FDIM))[lane];
        acc.x += blo(a);
        acc.y += bhi(a);
    }
    const float r = rinv[gb + v];
    const float2 sc = *(const float2*)&s1[l2];
    const float2 sh = *(const float2*)&sh1[l2];
    const float ox = fmaf(acc.x * r, sc.x, sh.x);
    const float oy = fmaf(acc.y * r, sc.y, sh.y);
    const unsigned w = (unsigned)f2bf(ox) | ((unsigned)f2bf(oy) << 16);
    ((unsigned*)(AGG3b + ((size_t)(gb + v)) * FDIM))[lane] = w;
}

// ---------------- GEMM1: H = relu( [A0|A1|A2](bf16) @ [W1;W2;W3] + sum b ), K=384 ----------------
__global__ __launch_bounds__(256) void k_gemm1(
    const unsigned short* __restrict__ AGG3b,
    const float* __restrict__ W1, const float* __restrict__ W2, const float* __restrict__ W3,
    const float* __restrict__ b1, const float* __restrict__ b2, const float* __restrict__ b3,
    float* __restrict__ H, int N) {
    __shared__ float At[16][64];
    __shared__ float Bt[16][128];
    const int t = threadIdx.x;
    const int row0 = blockIdx.x * 64;
    const int c0 = (t & 31) * 4;     // 0..124
    const int r0 = (t >> 5) * 8;     // 0..56
    float acc[8][4];
    #pragma unroll
    for (int r = 0; r < 8; ++r)
        #pragma unroll
        for (int c = 0; c < 4; ++c) acc[r][c] = 0.f;

    for (int kb = 0; kb < 24; ++kb) {      // K = 384, tiles of 16
        const int g = kb >> 3;
        const int kloc0 = (kb & 7) * 16;
        const unsigned short* Ag = AGG3b + (size_t)g * N * FDIM;
        const float* Wg = (g == 0) ? W1 : (g == 1) ? W2 : W3;
        {
            const int kk = t & 15;
            const int rb = t >> 4;          // 0..15
            #pragma unroll
            for (int it = 0; it < 4; ++it) {
                const int r = rb + it * 16;
                const int row = row0 + r;
                At[kk][r] = (row < N) ? bf2f(Ag[(size_t)row * FDIM + kloc0 + kk]) : 0.f;
            }
        }
        {
            const int n = t & 127;
            const int kkb = t >> 7;         // 0..1
            #pragma unroll
            for (int it = 0; it < 8; ++it) {
                const int kk = kkb + it * 2;
                Bt[kk][n] = Wg[(size_t)(kloc0 + kk) * 128 + n];
            }
        }
        __syncthreads();
        #pragma unroll
        for (int kk = 0; kk < 16; ++kk) {
            const float4 b  = *(const float4*)&Bt[kk][c0];
            const float4 a0 = *(const float4*)&At[kk][r0];
            const float4 a1 = *(const float4*)&At[kk][r0 + 4];
            const float a[8] = {a0.x, a0.y, a0.z, a0.w, a1.x, a1.y, a1.z, a1.w};
            #pragma unroll
            for (int r = 0; r < 8; ++r) {
                acc[r][0] = fmaf(a[r], b.x, acc[r][0]);
                acc[r][1] = fmaf(a[r], b.y, acc[r][1]);
                acc[r][2] = fmaf(a[r], b.z, acc[r][2]);
                acc[r][3] = fmaf(a[r], b.w, acc[r][3]);
            }
        }
        __syncthreads();
    }
    float4 base;
    base.x = b1[c0 + 0] + b2[c0 + 0] + b3[c0 + 0];
    base.y = b1[c0 + 1] + b2[c0 + 1] + b3[c0 + 1];
    base.z = b1[c0 + 2] + b2[c0 + 2] + b3[c0 + 2];
    base.w = b1[c0 + 3] + b2[c0 + 3] + b3[c0 + 3];
    #pragma unroll
    for (int r = 0; r < 8; ++r) {
        const int row = row0 + r0 + r;
        if (row < N) {
            float4 o;
            o.x = fmaxf(acc[r][0] + base.x, 0.f);
            o.y = fmaxf(acc[r][1] + base.y, 0.f);
            o.z = fmaxf(acc[r][2] + base.z, 0.f);
            o.w = fmaxf(acc[r][3] + base.w, 0.f);
            *(float4*)&H[(size_t)row * FDIM + c0] = o;
        }
    }
}

// ---------------- c2[g][n] = sum_k sh2[k] * Wg[k][n] ----------------
__global__ void k_c2(const float* __restrict__ sh2,
                     const float* __restrict__ W1, const float* __restrict__ W2,
                     const float* __restrict__ W3, float* __restrict__ c2) {
    const int t = threadIdx.x;   // 192
    const int g = t >> 6, n = t & 63;
    const float* W = (g == 0) ? W1 : (g == 1) ? W2 : W3;
    float s = 0.f;
    for (int k = 0; k < 128; ++k) s = fmaf(sh2[k], W[(size_t)k * ODIM + n], s);
    c2[g * ODIM + n] = s;
}

// ---------------- GEMM2 (BN2 scale fused): U_g = bf16( (H*s2) @ W_g2 + c2_g ) ----------------
__global__ __launch_bounds__(256) void k_gemm2(
    const float* __restrict__ H, const float* __restrict__ s2,
    const float* __restrict__ W1, const float* __restrict__ W2, const float* __restrict__ W3,
    const float* __restrict__ c2, unsigned short* __restrict__ Ub, int N) {
    __shared__ float At[16][64];
    __shared__ float Bt[16][64];
    const int t = threadIdx.x;
    const int g = blockIdx.y;
    const int row0 = blockIdx.x * 64;
    const int c0 = (t & 15) * 4;     // 0..60
    const int r0 = (t >> 4) * 4;     // 0..60
    const float* Wg = (g == 0) ? W1 : (g == 1) ? W2 : W3;
    float acc[4][4];
    #pragma unroll
    for (int r = 0; r < 4; ++r)
        #pragma unroll
        for (int c = 0; c < 4; ++c) acc[r][c] = 0.f;

    for (int kb = 0; kb < 8; ++kb) {       // K = 128
        const int k0 = kb * 16;
        {
            const int kk = t & 15;
            const int rb = t >> 4;          // 0..15
            const float sv = s2[k0 + kk];
            #pragma unroll
            for (int it = 0; it < 4; ++it) {
                const int r = rb + it * 16;
                const int row = row0 + r;
                At[kk][r] = (row < N) ? H[(size_t)row * FDIM + k0 + kk] * sv : 0.f;
            }
        }
        {
            const int n = t & 63;
            const int kkb = t >> 6;         // 0..3
            #pragma unroll
            for (int it = 0; it < 4; ++it) {
                const int kk = kkb + it * 4;
                Bt[kk][n] = Wg[(size_t)(k0 + kk) * ODIM + n];
            }
        }
        __syncthreads();
        #pragma unroll
        for (int kk = 0; kk < 16; ++kk) {
            const float4 b = *(const float4*)&Bt[kk][c0];
            const float4 a = *(const float4*)&At[kk][r0];
            const float av[4] = {a.x, a.y, a.z, a.w};
            #pragma unroll
            for (int r = 0; r < 4; ++r) {
                acc[r][0] = fmaf(av[r], b.x, acc[r][0]);
                acc[r][1] = fmaf(av[r], b.y, acc[r][1]);
                acc[r][2] = fmaf(av[r], b.z, acc[r][2]);
                acc[r][3] = fmaf(av[r], b.w, acc[r][3]);
            }
        }
        __syncthreads();
    }
    const float* cg = c2 + (size_t)g * ODIM;
    unsigned short* Ug = Ub + (size_t)g * N * ODIM;
    #pragma unroll
    for (int r = 0; r < 4; ++r) {
        const int row = row0 + r0 + r;
        if (row < N) {
            uint2 w;
            w.x = (unsigned)f2bf(acc[r][0] + cg[c0 + 0]) | ((unsigned)f2bf(acc[r][1] + cg[c0 + 1]) << 16);
            w.y = (unsigned)f2bf(acc[r][2] + cg[c0 + 2]) | ((unsigned)f2bf(acc[r][3] + cg[c0 + 3]) << 16);
            *(uint2*)&Ug[(size_t)row * ODIM + c0] = w;
        }
    }
}

// ---------------- layer-2 gather + combine (bf16 U rows) ----------------
__global__ __launch_bounds__(256) void k_gc64(
    const unsigned short* __restrict__ Ub,
    const int* __restrict__ nbr0, const int* __restrict__ nbr1, const int* __restrict__ nbr2,
    const int* __restrict__ off, const int* __restrict__ cend,
    const float* __restrict__ rinv,
    const float* __restrict__ b1, const float* __restrict__ b2, const float* __restrict__ b3,
    float* __restrict__ Z, int N) {
    const int wave = threadIdx.x >> 6;
    const int lane = threadIdx.x & 63;
    const int v = blockIdx.x * 4 + wave;
    if (v >= N) return;
    const size_t gs = (size_t)N * ODIM;
    float z = b1[lane] + b2[lane] + b3[lane];
    #pragma unroll
    for (int g = 0; g < 3; ++g) {
        const unsigned short* Ug = Ub + (size_t)g * gs;
        const int* nb = (g == 0) ? nbr0 : (g == 1) ? nbr1 : nbr2;
        const int i0 = off[g * N + v], i1 = cend[g * N + v];
        float s = bf2f(Ug[(size_t)v * ODIM + lane]);
        int i = i0;
        for (; i + 8 <= i1; i += 8) {
            const int u0 = nb[i],     u1 = nb[i + 1], u2 = nb[i + 2], u3 = nb[i + 3];
            const int u4 = nb[i + 4], u5 = nb[i + 5], u6 = nb[i + 6], u7 = nb[i + 7];
            const float a0 = bf2f(Ug[(size_t)u0 * ODIM + lane]);
            const float a1 = bf2f(Ug[(size_t)u1 * ODIM + lane]);
            const float a2 = bf2f(Ug[(size_t)u2 * ODIM + lane]);
            const float a3 = bf2f(Ug[(size_t)u3 * ODIM + lane]);
            const float a4 = bf2f(Ug[(size_t)u4 * ODIM + lane]);
            const float a5 = bf2f(Ug[(size_t)u5 * ODIM + lane]);
            const float a6 = bf2f(Ug[(size_t)u6 * ODIM + lane]);
            const float a7 = bf2f(Ug[(size_t)u7 * ODIM + lane]);
            s += ((a0 + a1) + (a2 + a3)) + ((a4 + a5) + (a6 + a7));
        }
        for (; i < i1; ++i) s += bf2f(Ug[(size_t)nb[i] * ODIM + lane]);
        z += s * rinv[g * N + v];
    }
    Z[(size_t)v * ODIM + lane] = z;
}

// ---------------- final: BN3 + sigmoid + row min-max + row L2, in place ----------------
__global__ __launch_bounds__(256) void k_final(float* __restrict__ Z,
                                               const float* __restrict__ scale,
                                               const float* __restrict__ shift, int N) {
    const int wave = threadIdx.x >> 6;
    const int lane = threadIdx.x & 63;
    const int row = blockIdx.x * 4 + wave;
    if (row >= N) return;
    float v = fmaf(Z[(size_t)row * ODIM + lane], scale[lane], shift[lane]);
    float s = 1.0f / (1.0f + expf(-v));
    float mn = s, mx = s;
    #pragma unroll
    for (int off = 32; off; off >>= 1) {
        mn = fminf(mn, __shfl_xor(mn, off, 64));
        mx = fmaxf(mx, __shfl_xor(mx, off, 64));
    }
    const float sc = (s - mn) / (mx - mn);
    float sq = sc * sc;
    #pragma unroll
    for (int off = 32; off; off >>= 1) sq += __shfl_xor(sq, off, 64);
    const float norm = fmaxf(sqrtf(sq), 1e-12f);
    Z[(size_t)row * ODIM + lane] = sc / norm;
}

extern "C" void kernel_launch(void* const* d_in, const int* in_sizes, int n_in,
                              void* d_out, int out_size, void* d_ws, size_t ws_size,
                              hipStream_t stream) {
    const float* x = (const float*)d_in[0];
    const int* src[3] = {(const int*)d_in[1], (const int*)d_in[3], (const int*)d_in[5]};
    const int* dst[3] = {(const int*)d_in[2], (const int*)d_in[4], (const int*)d_in[6]};
    const int E[3] = {in_sizes[1], in_sizes[3], in_sizes[5]};
    const int Etot = E[0] + E[1] + E[2];
    const float* W11 = (const float*)d_in[7];  const float* b11 = (const float*)d_in[8];
    const float* W21 = (const float*)d_in[9];  const float* b21 = (const float*)d_in[10];
    const float* W31 = (const float*)d_in[11]; const float* b31 = (const float*)d_in[12];
    const float* W12 = (const float*)d_in[13]; const float* b12 = (const float*)d_in[14];
    const float* W22 = (const float*)d_in[15]; const float* b22 = (const float*)d_in[16];
    const float* W32 = (const float*)d_in[17]; const float* b32 = (const float*)d_in[18];
    const float* g1  = (const float*)d_in[19]; const float* be1 = (const float*)d_in[20];
    const float* g2  = (const float*)d_in[21]; const float* be2 = (const float*)d_in[22];
    const float* g3  = (const float*)d_in[23]; const float* be3 = (const float*)d_in[24];
    const int N = in_sizes[0] / FDIM;
    float* Z = (float*)d_out;

    // ---- workspace layout ----
    float* ws   = (float*)d_ws;
    float* H    = ws;                          // N*128 f32
    unsigned short* xb = (unsigned short*)H;   // bf16 N*128, aliases H (dead before gemm1)
    float* REG  = H + (size_t)N * FDIM;        // 3*N*128 f32 region
    unsigned short* AGG3b = (unsigned short*)REG;   // bf16 3*N*128 (38.4 MB)
    unsigned short* Ub = (unsigned short*)REG;      // bf16 3*N*64, reuses after gemm1
    int2* ebuf = (int2*)REG;                                   // Etot int2 (pre-gather phase)
    unsigned* cnts = (unsigned*)(ebuf + (size_t)Etot);         // 3*NBK*BINB
    unsigned* bs   = cnts + (size_t)3 * NBK * BINB;            // 768
    float* rinv = REG + (size_t)3 * N * FDIM;  // 3N
    float* partial = rinv + (size_t)3 * N;     // 65536
    float* s1  = partial + 65536;  float* sh1 = s1 + 128;
    float* s2  = sh1 + 128;        float* sh2 = s2 + 128;
    float* s3  = sh2 + 128;        float* sh3 = s3 + 64;
    float* c2  = sh3 + 64;                     // 3*64
    int* off  = (int*)(c2 + 3 * ODIM);                    // 3N
    int* cend = off + (size_t)3 * N;                      // 3N
    int* nbr  = cend + (size_t)3 * N;                     // Etot
    int* nbrg[3];
    nbrg[0] = nbr;
    nbrg[1] = nbrg[0] + E[0];
    nbrg[2] = nbrg[1] + E[1];

    // ---- CSR build via bucket binning (single-writer nbr lines) ----
    const int nbuckets = (N + 255) >> 8;
    k_bincount<<<dim3(BINB, 3), 256, 0, stream>>>(dst[0], dst[1], dst[2],
                                                  E[0], E[1], E[2], cnts);
    k_sa<<<3 * NBK * BINB / 512, 256, 0, stream>>>(cnts, bs);
    k_sb<<<1, 1024, 0, stream>>>(bs, 3 * NBK * BINB / 512);
    k_sc<<<3 * NBK * BINB / 512, 256, 0, stream>>>(cnts, bs);
    k_binplace<<<dim3(BINB, 3), 256, 0, stream>>>(src[0], dst[0], src[1], dst[1],
                                                  src[2], dst[2], E[0], E[1], E[2],
                                                  cnts, ebuf);
    k_build<<<dim3(nbuckets, 3), 256, 0, stream>>>(ebuf, cnts, Etot, E[0], E[1],
                                                   off, cend, rinv,
                                                   nbrg[0], nbrg[1], nbrg[2], N);

    // ---- BN1 stats + fused bf16 conversion of x ----
    k_colstats_cvt<<<256, 128, 0, stream>>>(x, N, partial, xb);
    k_colstats_fin<128><<<1, 128, 0, stream>>>(partial, 256, N, g1, be1, s1, sh1);

    // ---- layer 1: 3-graph bf16 gather (bf16 out) -> single K=384 GEMM ----
    const int gblocks = (N + 3) / 4;
    k_gather3<<<dim3(gblocks, 3), 256, 0, stream>>>(xb, nbrg[0], nbrg[1], nbrg[2],
                                                    off, cend, rinv, s1, sh1, AGG3b, N);
    k_gemm1<<<(N + 63) / 64, 256, 0, stream>>>(AGG3b, W11, W21, W31, b11, b21, b31, H, N);

    // ---- BN2 stats (scale fused into GEMM2 A-load, shift folded via c2) ----
    k_colstats<128><<<256, 128, 0, stream>>>(H, N, partial);
    k_colstats_fin<128><<<1, 128, 0, stream>>>(partial, 256, N, g2, be2, s2, sh2);
    k_c2<<<1, 192, 0, stream>>>(sh2, W12, W22, W32, c2);

    // ---- layer 2: GEMM first (bf16 U over dead AGG3b), then bf16 gather+combine ----
    dim3 grid2((N + 63) / 64, 3);
    k_gemm2<<<grid2, 256, 0, stream>>>(H, s2, W12, W22, W32, c2, Ub, N);
    k_gc64<<<gblocks, 256, 0, stream>>>(Ub, nbrg[0], nbrg[1], nbrg[2], off, cend, rinv,
                                        b12, b22, b32, Z, N);

    // ---- BN3 + epilogue ----
    k_colstats<64><<<256, 64, 0, stream>>>(Z, N, partial);
    k_colstats_fin<64><<<1, 64, 0, stream>>>(partial, 256, N, g3, be3, s3, sh3);
    k_final<<<(N + 3) / 4, 256, 0, stream>>>(Z, s3, sh3, N);
}

// Round 11
// 685.414 us; speedup vs baseline: 1.7668x; 1.1073x over previous
//
#include <hip/hip_runtime.h>
#include <math.h>

constexpr int FDIM = 128;   // IN == HID
constexpr int ODIM = 64;    // NC
constexpr int BINB = 512;   // binning blocks per graph
constexpr int NBK  = 256;   // max buckets (256 nodes each -> N <= 65536)

typedef short bf16x8 __attribute__((ext_vector_type(8)));   // 8 bf16 in 4 VGPRs
typedef float f32x4  __attribute__((ext_vector_type(4)));

// bf16 helpers (RNE pack, bit-shift unpack)
__device__ inline unsigned short f2bf(float f) {
    unsigned u = __float_as_uint(f);
    u = (u + 0x7fffu + ((u >> 16) & 1u)) >> 16;
    return (unsigned short)u;
}
__device__ inline float bf2f(unsigned short s) { return __uint_as_float(((unsigned)s) << 16); }
__device__ inline float blo(unsigned v) { return __uint_as_float(v << 16); }
__device__ inline float bhi(unsigned v) { return __uint_as_float(v & 0xffff0000u); }

// ---------------- column stats (deterministic two-stage) ----------------
template<int C>
__global__ void k_colstats(const float* __restrict__ X, int N, float* __restrict__ partial) {
    const int c = threadIdx.x;          // blockDim.x == C
    const int nb = gridDim.x;
    const int rows_per = (N + nb - 1) / nb;
    const int r0 = blockIdx.x * rows_per;
    const int r1 = min(N, r0 + rows_per);
    float s = 0.f, ss = 0.f;
    for (int r = r0; r < r1; ++r) {
        float v = X[(size_t)r * C + c];
        s += v;
        ss += v * v;
    }
    partial[(size_t)blockIdx.x * (2 * C) + c]     = s;
    partial[(size_t)blockIdx.x * (2 * C) + C + c] = ss;
}

// BN1 variant: also emits bf16 copy of X (each element read exactly once)
__global__ void k_colstats_cvt(const float* __restrict__ X, int N,
                               float* __restrict__ partial, unsigned short* __restrict__ XB) {
    const int c = threadIdx.x;          // blockDim.x == 128
    const int nb = gridDim.x;
    const int rows_per = (N + nb - 1) / nb;
    const int r0 = blockIdx.x * rows_per;
    const int r1 = min(N, r0 + rows_per);
    float s = 0.f, ss = 0.f;
    for (int r = r0; r < r1; ++r) {
        float v = X[(size_t)r * 128 + c];
        s += v;
        ss += v * v;
        XB[(size_t)r * 128 + c] = f2bf(v);
    }
    partial[(size_t)blockIdx.x * 256 + c]       = s;
    partial[(size_t)blockIdx.x * 256 + 128 + c] = ss;
}

template<int C>
__global__ void k_colstats_fin(const float* __restrict__ partial, int nb, int N,
                               const float* __restrict__ gamma, const float* __restrict__ beta,
                               float* __restrict__ scale, float* __restrict__ shift) {
    const int c = threadIdx.x;          // blockDim.x == C
    float s = 0.f, ss = 0.f;
    for (int b = 0; b < nb; ++b) {
        s  += partial[(size_t)b * (2 * C) + c];
        ss += partial[(size_t)b * (2 * C) + C + c];
    }
    const float mu  = s / (float)N;
    const float var = ss / (float)N - mu * mu;
    const float sc  = gamma[c] * rsqrtf(var + 1e-5f);
    scale[c] = sc;
    shift[c] = beta[c] - mu * sc;
}

// ---------------- weights -> bf16 transposed: WTb[g][n][k] = bf16(Wg[k][n]) ----------------
__global__ void k_wt(const float* __restrict__ W1, const float* __restrict__ W2,
                     const float* __restrict__ W3, unsigned short* __restrict__ WTb) {
    const int g = blockIdx.y;
    const float* W = (g == 0) ? W1 : (g == 1) ? W2 : W3;
    const int id = blockIdx.x * 256 + threadIdx.x;   // 0..16383
    const int n = id >> 7, k = id & 127;
    WTb[(size_t)g * 16384 + (size_t)n * 128 + k] = f2bf(W[(size_t)k * 128 + n]);
}

// ================= CSR build via bucket binning (single-writer nbr lines) =================
__global__ __launch_bounds__(256) void k_bincount(
    const int* __restrict__ d0, const int* __restrict__ d1, const int* __restrict__ d2,
    int e0, int e1, int e2, unsigned* __restrict__ cnts) {
    const int g = blockIdx.y, blk = blockIdx.x, t = threadIdx.x;
    const int* dst = (g == 0) ? d0 : (g == 1) ? d1 : d2;
    const int E = (g == 0) ? e0 : (g == 1) ? e1 : e2;
    __shared__ unsigned hist[NBK];
    hist[t] = 0;
    __syncthreads();
    const int chunk = (E + BINB - 1) / BINB;
    const int i0 = blk * chunk, i1 = min(E, i0 + chunk);
    for (int i = i0 + t; i < i1; i += 256) atomicAdd(&hist[((unsigned)dst[i]) >> 8], 1u);
    __syncthreads();
    cnts[((size_t)(g * NBK + t)) * BINB + blk] = hist[t];
}

__global__ __launch_bounds__(256) void k_sa(const unsigned* __restrict__ cnts,
                                            unsigned* __restrict__ bs) {
    const int blk = blockIdx.x, t = threadIdx.x;
    unsigned s = cnts[(size_t)blk * 512 + t] + cnts[(size_t)blk * 512 + 256 + t];
    __shared__ unsigned red[256];
    red[t] = s;
    __syncthreads();
    for (int o = 128; o; o >>= 1) {
        if (t < o) red[t] += red[t + o];
        __syncthreads();
    }
    if (t == 0) bs[blk] = red[0];
}

__global__ void k_sb(unsigned* __restrict__ bs, int n) {
    const int t = threadIdx.x;
    __shared__ unsigned ps[1024];
    unsigned v = (t < n) ? bs[t] : 0u;
    ps[t] = v;
    __syncthreads();
    for (int o = 1; o < 1024; o <<= 1) {
        const unsigned a = (t >= o) ? ps[t - o] : 0u;
        __syncthreads();
        ps[t] += a;
        __syncthreads();
    }
    if (t < n) bs[t] = ps[t] - v;
}

__global__ __launch_bounds__(256) void k_sc(unsigned* __restrict__ cnts,
                                            const unsigned* __restrict__ bs) {
    const int blk = blockIdx.x, t = threadIdx.x;
    const size_t base = (size_t)blk * 512;
    const unsigned e0v = cnts[base + 2 * t];
    const unsigned e1v = cnts[base + 2 * t + 1];
    const unsigned pair = e0v + e1v;
    __shared__ unsigned ps[256];
    ps[t] = pair;
    __syncthreads();
    for (int o = 1; o < 256; o <<= 1) {
        const unsigned a = (t >= o) ? ps[t - o] : 0u;
        __syncthreads();
        ps[t] += a;
        __syncthreads();
    }
    const unsigned ex = ps[t] - pair + bs[blk];
    cnts[base + 2 * t]     = ex;
    cnts[base + 2 * t + 1] = ex + e0v;
}

__global__ __launch_bounds__(256) void k_binplace(
    const int* __restrict__ s0, const int* __restrict__ d0,
    const int* __restrict__ s1, const int* __restrict__ d1,
    const int* __restrict__ s2, const int* __restrict__ d2,
    int e0, int e1, int e2, const unsigned* __restrict__ pos, int2* __restrict__ ebuf) {
    const int g = blockIdx.y, blk = blockIdx.x, t = threadIdx.x;
    const int* src = (g == 0) ? s0 : (g == 1) ? s1 : s2;
    const int* dst = (g == 0) ? d0 : (g == 1) ? d1 : d2;
    const int E = (g == 0) ? e0 : (g == 1) ? e1 : e2;
    __shared__ unsigned cur[NBK];
    cur[t] = pos[((size_t)(g * NBK + t)) * BINB + blk];
    __syncthreads();
    const int chunk = (E + BINB - 1) / BINB;
    const int i0 = blk * chunk, i1 = min(E, i0 + chunk);
    for (int i = i0 + t; i < i1; i += 256) {
        const int dv = dst[i];
        const unsigned p = atomicAdd(&cur[((unsigned)dv) >> 8], 1u);
        ebuf[p] = make_int2(src[i], dv);
    }
}

__global__ __launch_bounds__(256) void k_build(
    const int2* __restrict__ ebuf, const unsigned* __restrict__ pos,
    int etot, int e0, int e1,
    int* __restrict__ off, int* __restrict__ cend, float* __restrict__ rinv,
    int* __restrict__ n0, int* __restrict__ n1, int* __restrict__ n2, int N) {
    const int g = blockIdx.y, b = blockIdx.x, t = threadIdx.x;
    const int v0 = b << 8;
    const int gbase = (g == 0) ? 0 : ((g == 1) ? e0 : e0 + e1);
    int* nbr = (g == 0) ? n0 : ((g == 1) ? n1 : n2);
    const int cell = g * NBK + b;
    const unsigned seg0 = pos[(size_t)cell * BINB];
    const unsigned seg1 = (cell + 1 < 3 * NBK) ? pos[(size_t)(cell + 1) * BINB] : (unsigned)etot;

    __shared__ unsigned deg[NBK];
    __shared__ unsigned ps[NBK];
    __shared__ unsigned cur[NBK];
    deg[t] = 0;
    __syncthreads();
    for (unsigned i = seg0 + t; i < seg1; i += 256) atomicAdd(&deg[ebuf[i].y - v0], 1u);
    __syncthreads();
    const unsigned dv = deg[t];
    ps[t] = dv;
    __syncthreads();
    for (int o = 1; o < 256; o <<= 1) {
        const unsigned a = (t >= o) ? ps[t - o] : 0u;
        __syncthreads();
        ps[t] += a;
        __syncthreads();
    }
    const unsigned ex = ps[t] - dv;     // exclusive within bucket
    const int nbase = (int)seg0 - gbase;
    const int node = v0 + t;
    if (node < N) {
        off[(size_t)g * N + node]  = nbase + (int)ex;
        cend[(size_t)g * N + node] = nbase + (int)(ex + dv);
        rinv[(size_t)g * N + node] = 1.0f / ((float)dv + 1.0f);
    }
    cur[t] = ex;
    __syncthreads();
    for (unsigned i = seg0 + t; i < seg1; i += 256) {
        const int2 e = ebuf[i];
        const unsigned p = atomicAdd(&cur[e.y - v0], 1u);
        nbr[nbase + (int)p] = e.x;
    }
}

// ---------------- gather (bf16 x rows, 3 graphs via blockIdx.y), BN1 fused, bf16 out ----------------
__global__ __launch_bounds__(256) void k_gather3(
    const unsigned short* __restrict__ XB,
    const int* __restrict__ nbr0, const int* __restrict__ nbr1, const int* __restrict__ nbr2,
    const int* __restrict__ off, const int* __restrict__ cend,
    const float* __restrict__ rinv, const float* __restrict__ s1,
    const float* __restrict__ sh1, unsigned short* __restrict__ AGG3b, int N) {
    const int g = blockIdx.y;
    const int* nbr = (g == 0) ? nbr0 : (g == 1) ? nbr1 : nbr2;
    const int gb = g * N;
    const int wave = threadIdx.x >> 6;
    const int lane = threadIdx.x & 63;
    const int v = blockIdx.x * 4 + wave;
    if (v >= N) return;
    const int i0 = off[gb + v], i1 = cend[gb + v];
    const int l2 = lane * 2;
    unsigned sv = ((const unsigned*)(XB + (size_t)v * FDIM))[lane];
    float2 acc;
    acc.x = blo(sv);
    acc.y = bhi(sv);
    int i = i0;
    for (; i + 8 <= i1; i += 8) {
        const int u0 = nbr[i],     u1 = nbr[i + 1], u2 = nbr[i + 2], u3 = nbr[i + 3];
        const int u4 = nbr[i + 4], u5 = nbr[i + 5], u6 = nbr[i + 6], u7 = nbr[i + 7];
        const unsigned a0 = ((const unsigned*)(XB + (size_t)u0 * FDIM))[lane];
        const unsigned a1 = ((const unsigned*)(XB + (size_t)u1 * FDIM))[lane];
        const unsigned a2 = ((const unsigned*)(XB + (size_t)u2 * FDIM))[lane];
        const unsigned a3 = ((const unsigned*)(XB + (size_t)u3 * FDIM))[lane];
        const unsigned a4 = ((const unsigned*)(XB + (size_t)u4 * FDIM))[lane];
        const unsigned a5 = ((const unsigned*)(XB + (size_t)u5 * FDIM))[lane];
        const unsigned a6 = ((const unsigned*)(XB + (size_t)u6 * FDIM))[lane];
        const unsigned a7 = ((const unsigned*)(XB + (size_t)u7 * FDIM))[lane];
        acc.x += ((blo(a0) + blo(a1)) + (blo(a2) + blo(a3))) + ((blo(a4) + blo(a5)) + (blo(a6) + blo(a7)));
        acc.y += ((bhi(a0) + bhi(a1)) + (bhi(a2) + bhi(a3))) + ((bhi(a4) + bhi(a5)) + (bhi(a6) + bhi(a7)));
    }
    for (; i < i1; ++i) {
        const unsigned a = ((const unsigned*)(XB + (size_t)nbr[i] * FDIM))[lane];
        acc.x += blo(a);
        acc.y += bhi(a);
    }
    const float r = rinv[gb + v];
    const float2 sc = *(const float2*)&s1[l2];
    const float2 sh = *(const float2*)&sh1[l2];
    const float ox = fmaf(acc.x * r, sc.x, sh.x);
    const float oy = fmaf(acc.y * r, sc.y, sh.y);
    const unsigned w = (unsigned)f2bf(ox) | ((unsigned)f2bf(oy) << 16);
    ((unsigned*)(AGG3b + ((size_t)(gb + v)) * FDIM))[lane] = w;
}

// ---------------- GEMM1 (MFMA bf16): H = relu( [A0|A1|A2] @ [W1;W2;W3] + sum b ), K=384 ----------------
// A bf16 (AGG3b), W bf16 transposed (WTb[n][k]). 64x128 tile, 4 waves, 16x16x32 mfma.
__global__ __launch_bounds__(256) void k_gemm1(
    const unsigned short* __restrict__ AGG3b, const unsigned short* __restrict__ WTb,
    const float* __restrict__ b1, const float* __restrict__ b2, const float* __restrict__ b3,
    float* __restrict__ H, int N) {
    constexpr int AST = 40;                 // padded row stride in shorts (80 B, 16B-aligned)
    __shared__ __align__(16) unsigned short As[64 * AST];    //  5120 B
    __shared__ __align__(16) unsigned short Bs[128 * AST];   // 10240 B
    const int t = threadIdx.x;
    const int w = t >> 6, l = t & 63;
    const int row0 = blockIdx.x * 64;
    const int cl = l & 15;                  // frag row/col index
    const int hi = l >> 4;                  // 0..3 -> k-subgroup
    f32x4 acc[8] = {};                      // 8 col-tiles of 16

    for (int g = 0; g < 3; ++g) {
        const unsigned short* Ag = AGG3b + (size_t)g * N * FDIM;
        const unsigned short* Wg = WTb + (size_t)g * 16384;
        for (int kb = 0; kb < 4; ++kb) {
            const int k0 = kb * 32;
            // stage A: 64 rows x 32 k (each thread one uint4 = 8 bf16)
            {
                const int r = t >> 2, h = t & 3;
                const int row = row0 + r;
                uint4 v = make_uint4(0u, 0u, 0u, 0u);
                if (row < N) v = *(const uint4*)(Ag + (size_t)row * FDIM + k0 + h * 8);
                *(uint4*)(As + r * AST + h * 8) = v;
            }
            // stage B: 128 cols x 32 k (each thread two uint4)
            {
                const int c = t >> 1, p = t & 1;
                const uint4 v0 = *(const uint4*)(Wg + (size_t)c * 128 + k0 + p * 16);
                const uint4 v1 = *(const uint4*)(Wg + (size_t)c * 128 + k0 + p * 16 + 8);
                *(uint4*)(Bs + c * AST + p * 16)     = v0;
                *(uint4*)(Bs + c * AST + p * 16 + 8) = v1;
            }
            __syncthreads();
            const bf16x8 af = *(const bf16x8*)(As + (w * 16 + cl) * AST + hi * 8);
            #pragma unroll
            for (int c = 0; c < 8; ++c) {
                const bf16x8 bf = *(const bf16x8*)(Bs + (c * 16 + cl) * AST + hi * 8);
                acc[c] = __builtin_amdgcn_mfma_f32_16x16x32_bf16(af, bf, acc[c], 0, 0, 0);
            }
            __syncthreads();
        }
    }
    // epilogue: D col = cl (within tile), row = 4*hi + reg
    #pragma unroll
    for (int c = 0; c < 8; ++c) {
        const int col = c * 16 + cl;
        const float bb = b1[col] + b2[col] + b3[col];
        #pragma unroll
        for (int r = 0; r < 4; ++r) {
            const int row = row0 + w * 16 + hi * 4 + r;
            if (row < N) H[(size_t)row * FDIM + col] = fmaxf(acc[c][r] + bb, 0.f);
        }
    }
}

// ---------------- c2[g][n] = sum_k sh2[k] * Wg[k][n] ----------------
__global__ void k_c2(const float* __restrict__ sh2,
                     const float* __restrict__ W1, const float* __restrict__ W2,
                     const float* __restrict__ W3, float* __restrict__ c2) {
    const int t = threadIdx.x;   // 192
    const int g = t >> 6, n = t & 63;
    const float* W = (g == 0) ? W1 : (g == 1) ? W2 : W3;
    float s = 0.f;
    for (int k = 0; k < 128; ++k) s = fmaf(sh2[k], W[(size_t)k * ODIM + n], s);
    c2[g * ODIM + n] = s;
}

// ---------------- GEMM2 (BN2 scale fused): U_g = bf16( (H*s2) @ W_g2 + c2_g ) ----------------
__global__ __launch_bounds__(256) void k_gemm2(
    const float* __restrict__ H, const float* __restrict__ s2,
    const float* __restrict__ W1, const float* __restrict__ W2, const float* __restrict__ W3,
    const float* __restrict__ c2, unsigned short* __restrict__ Ub, int N) {
    __shared__ float At[16][64];
    __shared__ float Bt[16][64];
    const int t = threadIdx.x;
    const int g = blockIdx.y;
    const int row0 = blockIdx.x * 64;
    const int c0 = (t & 15) * 4;     // 0..60
    const int r0 = (t >> 4) * 4;     // 0..60
    const float* Wg = (g == 0) ? W1 : (g == 1) ? W2 : W3;
    float acc[4][4];
    #pragma unroll
    for (int r = 0; r < 4; ++r)
        #pragma unroll
        for (int c = 0; c < 4; ++c) acc[r][c] = 0.f;

    for (int kb = 0; kb < 8; ++kb) {       // K = 128
        const int k0 = kb * 16;
        {
            const int kk = t & 15;
            const int rb = t >> 4;          // 0..15
            const float sv = s2[k0 + kk];
            #pragma unroll
            for (int it = 0; it < 4; ++it) {
                const int r = rb + it * 16;
                const int row = row0 + r;
                At[kk][r] = (row < N) ? H[(size_t)row * FDIM + k0 + kk] * sv : 0.f;
            }
        }
        {
            const int n = t & 63;
            const int kkb = t >> 6;         // 0..3
            #pragma unroll
            for (int it = 0; it < 4; ++it) {
                const int kk = kkb + it * 4;
                Bt[kk][n] = Wg[(size_t)(k0 + kk) * ODIM + n];
            }
        }
        __syncthreads();
        #pragma unroll
        for (int kk = 0; kk < 16; ++kk) {
            const float4 b = *(const float4*)&Bt[kk][c0];
            const float4 a = *(const float4*)&At[kk][r0];
            const float av[4] = {a.x, a.y, a.z, a.w};
            #pragma unroll
            for (int r = 0; r < 4; ++r) {
                acc[r][0] = fmaf(av[r], b.x, acc[r][0]);
                acc[r][1] = fmaf(av[r], b.y, acc[r][1]);
                acc[r][2] = fmaf(av[r], b.z, acc[r][2]);
                acc[r][3] = fmaf(av[r], b.w, acc[r][3]);
            }
        }
        __syncthreads();
    }
    const float* cg = c2 + (size_t)g * ODIM;
    unsigned short* Ug = Ub + (size_t)g * N * ODIM;
    #pragma unroll
    for (int r = 0; r < 4; ++r) {
        const int row = row0 + r0 + r;
        if (row < N) {
            uint2 w;
            w.x = (unsigned)f2bf(acc[r][0] + cg[c0 + 0]) | ((unsigned)f2bf(acc[r][1] + cg[c0 + 1]) << 16);
            w.y = (unsigned)f2bf(acc[r][2] + cg[c0 + 2]) | ((unsigned)f2bf(acc[r][3] + cg[c0 + 3]) << 16);
            *(uint2*)&Ug[(size_t)row * ODIM + c0] = w;
        }
    }
}

// ---------------- layer-2 gather + combine (bf16 U rows) ----------------
__global__ __launch_bounds__(256) void k_gc64(
    const unsigned short* __restrict__ Ub,
    const int* __restrict__ nbr0, const int* __restrict__ nbr1, const int* __restrict__ nbr2,
    const int* __restrict__ off, const int* __restrict__ cend,
    const float* __restrict__ rinv,
    const float* __restrict__ b1, const float* __restrict__ b2, const float* __restrict__ b3,
    float* __restrict__ Z, int N) {
    const int wave = threadIdx.x >> 6;
    const int lane = threadIdx.x & 63;
    const int v = blockIdx.x * 4 + wave;
    if (v >= N) return;
    const size_t gs = (size_t)N * ODIM;
    float z = b1[lane] + b2[lane] + b3[lane];
    #pragma unroll
    for (int g = 0; g < 3; ++g) {
        const unsigned short* Ug = Ub + (size_t)g * gs;
        const int* nb = (g == 0) ? nbr0 : (g == 1) ? nbr1 : nbr2;
        const int i0 = off[g * N + v], i1 = cend[g * N + v];
        float s = bf2f(Ug[(size_t)v * ODIM + lane]);
        int i = i0;
        for (; i + 8 <= i1; i += 8) {
            const int u0 = nb[i],     u1 = nb[i + 1], u2 = nb[i + 2], u3 = nb[i + 3];
            const int u4 = nb[i + 4], u5 = nb[i + 5], u6 = nb[i + 6], u7 = nb[i + 7];
            const float a0 = bf2f(Ug[(size_t)u0 * ODIM + lane]);
            const float a1 = bf2f(Ug[(size_t)u1 * ODIM + lane]);
            const float a2 = bf2f(Ug[(size_t)u2 * ODIM + lane]);
            const float a3 = bf2f(Ug[(size_t)u3 * ODIM + lane]);
            const float a4 = bf2f(Ug[(size_t)u4 * ODIM + lane]);
            const float a5 = bf2f(Ug[(size_t)u5 * ODIM + lane]);
            const float a6 = bf2f(Ug[(size_t)u6 * ODIM + lane]);
            const float a7 = bf2f(Ug[(size_t)u7 * ODIM + lane]);
            s += ((a0 + a1) + (a2 + a3)) + ((a4 + a5) + (a6 + a7));
        }
        for (; i < i1; ++i) s += bf2f(Ug[(size_t)nb[i] * ODIM + lane]);
        z += s * rinv[g * N + v];
    }
    Z[(size_t)v * ODIM + lane] = z;
}

// ---------------- final: BN3 + sigmoid + row min-max + row L2, in place ----------------
__global__ __launch_bounds__(256) void k_final(float* __restrict__ Z,
                                               const float* __restrict__ scale,
                                               const float* __restrict__ shift, int N) {
    const int wave = threadIdx.x >> 6;
    const int lane = threadIdx.x & 63;
    const int row = blockIdx.x * 4 + wave;
    if (row >= N) return;
    float v = fmaf(Z[(size_t)row * ODIM + lane], scale[lane], shift[lane]);
    float s = 1.0f / (1.0f + expf(-v));
    float mn = s, mx = s;
    #pragma unroll
    for (int off = 32; off; off >>= 1) {
        mn = fminf(mn, __shfl_xor(mn, off, 64));
        mx = fmaxf(mx, __shfl_xor(mx, off, 64));
    }
    const float sc = (s - mn) / (mx - mn);
    float sq = sc * sc;
    #pragma unroll
    for (int off = 32; off; off >>= 1) sq += __shfl_xor(sq, off, 64);
    const float norm = fmaxf(sqrtf(sq), 1e-12f);
    Z[(size_t)row * ODIM + lane] = sc / norm;
}

extern "C" void kernel_launch(void* const* d_in, const int* in_sizes, int n_in,
                              void* d_out, int out_size, void* d_ws, size_t ws_size,
                              hipStream_t stream) {
    const float* x = (const float*)d_in[0];
    const int* src[3] = {(const int*)d_in[1], (const int*)d_in[3], (const int*)d_in[5]};
    const int* dst[3] = {(const int*)d_in[2], (const int*)d_in[4], (const int*)d_in[6]};
    const int E[3] = {in_sizes[1], in_sizes[3], in_sizes[5]};
    const int Etot = E[0] + E[1] + E[2];
    const float* W11 = (const float*)d_in[7];  const float* b11 = (const float*)d_in[8];
    const float* W21 = (const float*)d_in[9];  const float* b21 = (const float*)d_in[10];
    const float* W31 = (const float*)d_in[11]; const float* b31 = (const float*)d_in[12];
    const float* W12 = (const float*)d_in[13]; const float* b12 = (const float*)d_in[14];
    const float* W22 = (const float*)d_in[15]; const float* b22 = (const float*)d_in[16];
    const float* W32 = (const float*)d_in[17]; const float* b32 = (const float*)d_in[18];
    const float* g1  = (const float*)d_in[19]; const float* be1 = (const float*)d_in[20];
    const float* g2  = (const float*)d_in[21]; const float* be2 = (const float*)d_in[22];
    const float* g3  = (const float*)d_in[23]; const float* be3 = (const float*)d_in[24];
    const int N = in_sizes[0] / FDIM;
    float* Z = (float*)d_out;

    // ---- workspace layout ----
    float* ws   = (float*)d_ws;
    float* H    = ws;                          // N*128 f32
    unsigned short* xb = (unsigned short*)H;   // bf16 N*128, aliases H (dead before gemm1)
    float* REG  = H + (size_t)N * FDIM;        // 3*N*128 f32 region
    unsigned short* AGG3b = (unsigned short*)REG;   // bf16 3*N*128 (38.4 MB)
    unsigned short* Ub = (unsigned short*)REG;      // bf16 3*N*64, reuses after gemm1
    int2* ebuf = (int2*)REG;                                   // Etot int2 (pre-gather phase)
    unsigned* cnts = (unsigned*)(ebuf + (size_t)Etot);         // 3*NBK*BINB
    unsigned* bs   = cnts + (size_t)3 * NBK * BINB;            // 768
    float* rinv = REG + (size_t)3 * N * FDIM;  // 3N
    float* partial = rinv + (size_t)3 * N;     // 65536
    float* s1  = partial + 65536;  float* sh1 = s1 + 128;
    float* s2  = sh1 + 128;        float* sh2 = s2 + 128;
    float* s3  = sh2 + 128;        float* sh3 = s3 + 64;
    float* c2  = sh3 + 64;                     // 3*64
    unsigned short* WTb = (unsigned short*)(c2 + 3 * ODIM);   // bf16 3*128*128 (96 KB)
    int* off  = (int*)(WTb + (size_t)3 * 16384);          // 3N
    int* cend = off + (size_t)3 * N;                      // 3N
    int* nbr  = cend + (size_t)3 * N;                     // Etot
    int* nbrg[3];
    nbrg[0] = nbr;
    nbrg[1] = nbrg[0] + E[0];
    nbrg[2] = nbrg[1] + E[1];

    // ---- CSR build via bucket binning (single-writer nbr lines) ----
    const int nbuckets = (N + 255) >> 8;
    k_bincount<<<dim3(BINB, 3), 256, 0, stream>>>(dst[0], dst[1], dst[2],
                                                  E[0], E[1], E[2], cnts);
    k_sa<<<3 * NBK * BINB / 512, 256, 0, stream>>>(cnts, bs);
    k_sb<<<1, 1024, 0, stream>>>(bs, 3 * NBK * BINB / 512);
    k_sc<<<3 * NBK * BINB / 512, 256, 0, stream>>>(cnts, bs);
    k_binplace<<<dim3(BINB, 3), 256, 0, stream>>>(src[0], dst[0], src[1], dst[1],
                                                  src[2], dst[2], E[0], E[1], E[2],
                                                  cnts, ebuf);
    k_build<<<dim3(nbuckets, 3), 256, 0, stream>>>(ebuf, cnts, Etot, E[0], E[1],
                                                   off, cend, rinv,
                                                   nbrg[0], nbrg[1], nbrg[2], N);

    // ---- BN1 stats + fused bf16 conversion of x; bf16 transposed weights ----
    k_colstats_cvt<<<256, 128, 0, stream>>>(x, N, partial, xb);
    k_colstats_fin<128><<<1, 128, 0, stream>>>(partial, 256, N, g1, be1, s1, sh1);
    k_wt<<<dim3(64, 3), 256, 0, stream>>>(W11, W21, W31, WTb);

    // ---- layer 1: 3-graph bf16 gather (bf16 out) -> MFMA K=384 GEMM ----
    const int gblocks = (N + 3) / 4;
    k_gather3<<<dim3(gblocks, 3), 256, 0, stream>>>(xb, nbrg[0], nbrg[1], nbrg[2],
                                                    off, cend, rinv, s1, sh1, AGG3b, N);
    k_gemm1<<<(N + 63) / 64, 256, 0, stream>>>(AGG3b, WTb, b11, b21, b31, H, N);

    // ---- BN2 stats (scale fused into GEMM2 A-load, shift folded via c2) ----
    k_colstats<128><<<256, 128, 0, stream>>>(H, N, partial);
    k_colstats_fin<128><<<1, 128, 0, stream>>>(partial, 256, N, g2, be2, s2, sh2);
    k_c2<<<1, 192, 0, stream>>>(sh2, W12, W22, W32, c2);

    // ---- layer 2: GEMM first (bf16 U over dead AGG3b), then bf16 gather+combine ----
    dim3 grid2((N + 63) / 64, 3);
    k_gemm2<<<grid2, 256, 0, stream>>>(H, s2, W12, W22, W32, c2, Ub, N);
    k_gc64<<<gblocks, 256, 0, stream>>>(Ub, nbrg[0], nbrg[1], nbrg[2], off, cend, rinv,
                                        b12, b22, b32, Z, N);

    // ---- BN3 + epilogue ----
    k_colstats<64><<<256, 64, 0, stream>>>(Z, N, partial);
    k_colstats_fin<64><<<1, 64, 0, stream>>>(partial, 256, N, g3, be3, s3, sh3);
    k_final<<<(N + 3) / 4, 256, 0, stream>>>(Z, s3, sh3, N);
}